// Round 1
// baseline (236.947 us; speedup 1.0000x reference)
//
#include <hip/hip_runtime.h>

// Problem constants (match reference setup_inputs)
#define BB 4
#define NN 10000
#define FF 128
#define UU 128
#define EE 160000

typedef __bf16 bf16x8 __attribute__((ext_vector_type(8)));
typedef float  f32x4  __attribute__((ext_vector_type(4)));

// ---------------------------------------------------------------------------
// CSR build: degree count
__global__ __launch_bounds__(256) void k_deg(const int* __restrict__ eidx,
                                             int* __restrict__ deg) {
  int e = blockIdx.x * 256 + threadIdx.x;
  if (e < EE) atomicAdd(&deg[eidx[2 * e]], 1);
}

// Single-block exclusive scan over N=10000 degrees -> offsets (+ cursor copy)
__global__ __launch_bounds__(1024) void k_scan(const int* __restrict__ deg,
                                               int* __restrict__ offs,
                                               int* __restrict__ cursor) {
  __shared__ int sums[1024];
  const int t = threadIdx.x;
  const int base = t * 10;
  int local[10];
  int s = 0;
#pragma unroll
  for (int i = 0; i < 10; ++i) {
    int v = (base + i < NN) ? deg[base + i] : 0;
    local[i] = s;
    s += v;
  }
  sums[t] = s;
  __syncthreads();
  for (int off = 1; off < 1024; off <<= 1) {
    int v = 0;
    if (t >= off) v = sums[t - off];
    __syncthreads();
    sums[t] += v;
    __syncthreads();
  }
  int pre = (t == 0) ? 0 : sums[t - 1];
#pragma unroll
  for (int i = 0; i < 10; ++i) {
    int idx = base + i;
    if (idx < NN) {
      int o = pre + local[i];
      offs[idx] = o;
      cursor[idx] = o;
    }
  }
  if (t == 1023) offs[NN] = sums[1023];  // == EE
}

__global__ __launch_bounds__(256) void k_fill(const int* __restrict__ eidx,
                                              int* __restrict__ cursor,
                                              int* __restrict__ elist) {
  int e = blockIdx.x * 256 + threadIdx.x;
  if (e < EE) {
    int s = eidx[2 * e];
    int pos = atomicAdd(&cursor[s], 1);
    elist[pos] = e;
  }
}

// ---------------------------------------------------------------------------
// GEMM1: h = relu(nf @ W_t + b_t)   (M=B*N=40000, K=128, N=128), bf16 MFMA.
// Fused: p[row] = h_row . Wa[0:128],  q[row] = h_row . Wa[128:256]
// LDS B layout: pre-swizzled frags. region r=(k0/32)*8+c holds 64 lanes x 8 bf16.
__global__ __launch_bounds__(256) void k_gemm_h(
    const float* __restrict__ nf, const float* __restrict__ Wt,
    const float* __restrict__ bt, const float* __restrict__ Wa,
    __bf16* __restrict__ h, float* __restrict__ p, float* __restrict__ q) {
  __shared__ __bf16 Bt[32 * 512];  // 32 KB
  const int tid = threadIdx.x;
  // stage W_t (128x128 fp32) -> swizzled bf16 frags
  for (int i = tid; i < FF * UU; i += 256) {
    int k = i >> 7, n = i & 127;
    int kc = k >> 5, kb = (k >> 3) & 3, j = k & 7;
    int c = n >> 4, ln = n & 15;
    int lane = ln | (kb << 4);
    Bt[((kc << 3) + c) * 512 + lane * 8 + j] = (__bf16)Wt[i];
  }
  __syncthreads();

  const int wid = tid >> 6, lane = tid & 63;
  const int lr = lane & 15, lg = lane >> 4;
  const int row0 = blockIdx.x * 64 + wid * 16;

  f32x4 acc[8];
#pragma unroll
  for (int c = 0; c < 8; ++c)
#pragma unroll
    for (int r = 0; r < 4; ++r) acc[c][r] = 0.f;

#pragma unroll
  for (int k0 = 0; k0 < 128; k0 += 32) {
    int kk = k0 + lg * 8;
    const float4* ap = (const float4*)(nf + (size_t)(row0 + lr) * 128 + kk);
    float4 a0 = ap[0], a1 = ap[1];
    bf16x8 af;
    af[0] = (__bf16)a0.x; af[1] = (__bf16)a0.y; af[2] = (__bf16)a0.z; af[3] = (__bf16)a0.w;
    af[4] = (__bf16)a1.x; af[5] = (__bf16)a1.y; af[6] = (__bf16)a1.z; af[7] = (__bf16)a1.w;
#pragma unroll
    for (int c = 0; c < 8; ++c) {
      bf16x8 bf = *(const bf16x8*)(Bt + (((k0 >> 5) << 3) + c) * 512 + lane * 8);
      acc[c] = __builtin_amdgcn_mfma_f32_16x16x32_bf16(af, bf, acc[c], 0, 0, 0);
    }
  }

  // epilogue: bias + relu, store bf16 h, accumulate p/q partials
  float pr[4] = {0.f, 0.f, 0.f, 0.f};
  float qr[4] = {0.f, 0.f, 0.f, 0.f};
#pragma unroll
  for (int c = 0; c < 8; ++c) {
    int col = c * 16 + lr;
    float bias = bt[col];
    float walo = Wa[col], wahi = Wa[128 + col];
#pragma unroll
    for (int r = 0; r < 4; ++r) {
      float v = acc[c][r] + bias;
      v = fmaxf(v, 0.f);
      int row = row0 + lg * 4 + r;
      h[(size_t)row * 128 + col] = (__bf16)v;
      pr[r] += v * walo;
      qr[r] += v * wahi;
    }
  }
#pragma unroll
  for (int r = 0; r < 4; ++r) {
    float pv = pr[r], qv = qr[r];
#pragma unroll
    for (int m = 1; m < 16; m <<= 1) {
      pv += __shfl_xor(pv, m);
      qv += __shfl_xor(qv, m);
    }
    if (lr == 0) {
      int row = row0 + lg * 4 + r;
      p[row] = pv;
      q[row] = qv;
    }
  }
}

// ---------------------------------------------------------------------------
// Edge attention: ex[b*E+e] = exp(tanh(p[b,src]+q[b,tgt]+b_a)); global sum -> S
__global__ __launch_bounds__(256) void k_att(const int* __restrict__ eidx,
                                             const float* __restrict__ p,
                                             const float* __restrict__ q,
                                             const float* __restrict__ ba,
                                             float* __restrict__ ex,
                                             float* __restrict__ S) {
  int tid = blockIdx.x * 256 + threadIdx.x;  // < B*E = 640000 exactly
  int b = tid / EE;
  int e = tid - b * EE;
  int s = eidx[2 * e], t = eidx[2 * e + 1];
  float a = p[b * NN + s] + q[b * NN + t] + ba[0];
  float v = __expf(tanhf(a));
  ex[tid] = v;
  // block reduction -> one atomic
  float vs = v;
#pragma unroll
  for (int m = 1; m < 64; m <<= 1) vs += __shfl_xor(vs, m);
  __shared__ float part[4];
  int wid = threadIdx.x >> 6, lane = threadIdx.x & 63;
  if (lane == 0) part[wid] = vs;
  __syncthreads();
  if (threadIdx.x == 0) atomicAdd(S, part[0] + part[1] + part[2] + part[3]);
}

// ---------------------------------------------------------------------------
// Aggregation: scattered[b,n,:] = sum_{e in CSR[n]} (ex[b,e]/S) * h[b,tgt[e],:]
// one wave per (b,n); lane covers 2 units via packed bf16x2 (uint).
__global__ __launch_bounds__(256) void k_agg(
    const int* __restrict__ eidx, const int* __restrict__ elist,
    const int* __restrict__ offs, const float* __restrict__ ex,
    const float* __restrict__ S, const __bf16* __restrict__ h,
    __bf16* __restrict__ scat) {
  const int wid = threadIdx.x >> 6, lane = threadIdx.x & 63;
  const int w = blockIdx.x * 4 + wid;  // < 40000
  const int b = w / NN;
  const int n = w - b * NN;
  const float invS = 1.0f / S[0];
  const int o0 = offs[n], o1 = offs[n + 1];
  float ax = 0.f, ay = 0.f;
  for (int base = o0; base < o1; base += 64) {
    int il = base + lane;
    int t_l = 0;
    float w_l = 0.f;
    if (il < o1) {
      int e_l = elist[il];
      t_l = eidx[2 * e_l + 1];
      w_l = ex[b * EE + e_l] * invS;
    }
    int cnt = min(64, o1 - base);
    for (int j = 0; j < cnt; ++j) {
      int t = __shfl(t_l, j);
      float wj = __shfl(w_l, j);
      const unsigned* hrow = (const unsigned*)(h + ((size_t)b * NN + t) * 128);
      unsigned hv = hrow[lane];
      float f0 = __uint_as_float(hv << 16);
      float f1 = __uint_as_float(hv & 0xffff0000u);
      ax = fmaf(wj, f0, ax);
      ay = fmaf(wj, f1, ay);
    }
  }
  // pack to bf16x2 (RNE) and store 4B/lane coalesced
  unsigned ux = __float_as_uint(ax);
  ux = (ux + 0x7fffu + ((ux >> 16) & 1u)) >> 16;
  unsigned uy = __float_as_uint(ay);
  uy = (uy + 0x7fffu + ((uy >> 16) & 1u)) >> 16;
  unsigned* srow = (unsigned*)(scat + (size_t)w * 128);
  srow[lane] = ux | (uy << 16);
}

// ---------------------------------------------------------------------------
// GEMM2: out = relu([h, scattered] @ W_c + b_c)  (M=40000, K=256, N=128)
__global__ __launch_bounds__(256) void k_gemm_out(
    const __bf16* __restrict__ h, const __bf16* __restrict__ scat,
    const float* __restrict__ Wc, const float* __restrict__ bc,
    float* __restrict__ out) {
  __shared__ __bf16 Bt[64 * 512];  // 64 KB
  const int tid = threadIdx.x;
  for (int i = tid; i < 256 * 128; i += 256) {
    int k = i >> 7, n = i & 127;
    int kc = k >> 5, kb = (k >> 3) & 3, j = k & 7;
    int c = n >> 4, ln = n & 15;
    int lane = ln | (kb << 4);
    Bt[((kc << 3) + c) * 512 + lane * 8 + j] = (__bf16)Wc[i];
  }
  __syncthreads();

  const int wid = tid >> 6, lane = tid & 63;
  const int lr = lane & 15, lg = lane >> 4;
  const int row0 = blockIdx.x * 64 + wid * 16;

  f32x4 acc[8];
#pragma unroll
  for (int c = 0; c < 8; ++c)
#pragma unroll
    for (int r = 0; r < 4; ++r) acc[c][r] = 0.f;

#pragma unroll
  for (int k0 = 0; k0 < 256; k0 += 32) {
    int kk = k0 + lg * 8;
    const __bf16* abase = (k0 < 128)
                              ? (h + (size_t)(row0 + lr) * 128 + kk)
                              : (scat + (size_t)(row0 + lr) * 128 + (kk - 128));
    bf16x8 af = *(const bf16x8*)abase;
#pragma unroll
    for (int c = 0; c < 8; ++c) {
      bf16x8 bf = *(const bf16x8*)(Bt + (((k0 >> 5) << 3) + c) * 512 + lane * 8);
      acc[c] = __builtin_amdgcn_mfma_f32_16x16x32_bf16(af, bf, acc[c], 0, 0, 0);
    }
  }

#pragma unroll
  for (int c = 0; c < 8; ++c) {
    int col = c * 16 + lr;
    float bias = bc[col];
#pragma unroll
    for (int r = 0; r < 4; ++r) {
      float v = acc[c][r] + bias;
      v = fmaxf(v, 0.f);
      int row = row0 + lg * 4 + r;
      out[(size_t)row * 128 + col] = v;
    }
  }
}

// ---------------------------------------------------------------------------
extern "C" void kernel_launch(void* const* d_in, const int* in_sizes, int n_in,
                              void* d_out, int out_size, void* d_ws,
                              size_t ws_size, hipStream_t stream) {
  const float* nf = (const float*)d_in[0];
  const int* eidx = (const int*)d_in[1];
  const float* Wt = (const float*)d_in[2];
  const float* bt = (const float*)d_in[3];
  const float* Wa = (const float*)d_in[4];
  const float* ba = (const float*)d_in[5];
  const float* Wc = (const float*)d_in[6];
  const float* bc = (const float*)d_in[7];
  float* out = (float*)d_out;

  char* w = (char*)d_ws;
  // workspace layout (256B aligned)
  float* S = (float*)(w + 0);               // 4 B (padded to 256)
  int* deg = (int*)(w + 256);               // 40000 B
  int* offs = (int*)(w + 40448);            // 40004 B
  int* cursor = (int*)(w + 80640);          // 40000 B
  int* elist = (int*)(w + 120832);          // 640000 B
  float* p = (float*)(w + 760832);          // 160000 B
  float* q = (float*)(w + 920832);          // 160000 B
  float* ex = (float*)(w + 1080832);        // 2560000 B
  __bf16* h = (__bf16*)(w + 3640832);       // 10240000 B
  __bf16* scat = (__bf16*)(w + 13880832);   // 10240000 B
  // total ~24.1 MB

  // zero S + deg (ws is re-poisoned to 0xAA before every timed launch)
  hipMemsetAsync(d_ws, 0, 40448, stream);

  k_deg<<<625, 256, 0, stream>>>(eidx, deg);
  k_scan<<<1, 1024, 0, stream>>>(deg, offs, cursor);
  k_fill<<<625, 256, 0, stream>>>(eidx, cursor, elist);
  k_gemm_h<<<625, 256, 0, stream>>>(nf, Wt, bt, Wa, h, p, q);
  k_att<<<2500, 256, 0, stream>>>(eidx, p, q, ba, ex, S);
  k_agg<<<10000, 256, 0, stream>>>(eidx, elist, offs, ex, S, h, scat);
  k_gemm_out<<<625, 256, 0, stream>>>(h, scat, Wc, bc, out);
}

// Round 2
// 198.745 us; speedup vs baseline: 1.1922x; 1.1922x over previous
//
#include <hip/hip_runtime.h>

// Problem constants (match reference setup_inputs)
#define BB 4
#define NN 10000
#define FF 128
#define UU 128
#define EE 160000

typedef __bf16 bf16x8 __attribute__((ext_vector_type(8)));
typedef float  f32x4  __attribute__((ext_vector_type(4)));

// ws layout (bytes)
#define WS_S      0         // float S (4 B)
#define WS_DEG    256       // int[10000]
#define WS_OFFS   40448     // int[10001]
#define WS_CUR    80640     // int[10000]
#define WS_ELIST  120832    // int[160000]
#define WS_P      760832    // float[40000]
#define WS_Q      920832    // float[40000]
#define WS_EX     1080832   // float[640000]
#define WS_BTG    3640832   // bf16 swizzled W_t (32 KB)
#define WS_BCG    3673600   // bf16 swizzled W_c (64 KB)
#define WS_HS     3739136   // bf16 hs[40000][256]  (h | scat interleaved)

// ---------------------------------------------------------------------------
// k_prep: zero S+deg; pre-swizzle W_t and W_c into bf16 MFMA-frag layout.
// Element (k,n) -> region (k>>5)*8 + (n>>4), lane = (n&15)|(((k>>3)&3)<<4),
// byte addr = region*1024 + lane*16 + (k&7)*2.
__global__ __launch_bounds__(256) void k_prep(const float* __restrict__ Wt,
                                              const float* __restrict__ Wc,
                                              char* __restrict__ ws) {
  const int gid = blockIdx.x * 256 + threadIdx.x;  // 8 blocks -> 2048 threads
  // zero S + deg: bytes [0, 40448) = 2528 uint4
  uint4* zp = (uint4*)ws;
  uint4 z = {0u, 0u, 0u, 0u};
  for (int i = gid; i < 2528; i += 2048) zp[i] = z;

  __bf16* Btg = (__bf16*)(ws + WS_BTG);
  __bf16* Bcg = (__bf16*)(ws + WS_BCG);
  // W_t: 2048 items (one per thread), each = 8 k's for one n
  {
    int i = gid;
    int n = i & 127, kb8 = i >> 7;  // kb8 in [0,16)
    int kc = kb8 >> 2, kbq = kb8 & 3;
    int lane = (n & 15) | (kbq << 4), c = n >> 4;
    const float* src = Wt + (size_t)kb8 * 8 * 128 + n;
    bf16x8 v;
#pragma unroll
    for (int j = 0; j < 8; ++j) v[j] = (__bf16)src[(size_t)j * 128];
    *(bf16x8*)(Btg + ((kc * 8 + c) * 512 + lane * 8)) = v;
  }
  // W_c: 4096 items (two per thread)
#pragma unroll
  for (int it = 0; it < 2; ++it) {
    int i = gid + it * 2048;
    int n = i & 127, kb8 = i >> 7;  // kb8 in [0,32)
    int kc = kb8 >> 2, kbq = kb8 & 3;
    int lane = (n & 15) | (kbq << 4), c = n >> 4;
    const float* src = Wc + (size_t)kb8 * 8 * 128 + n;
    bf16x8 v;
#pragma unroll
    for (int j = 0; j < 8; ++j) v[j] = (__bf16)src[(size_t)j * 128];
    *(bf16x8*)(Bcg + ((kc * 8 + c) * 512 + lane * 8)) = v;
  }
}

// ---------------------------------------------------------------------------
// GEMM1: h = relu(nf @ W_t + b_t), fused p/q = h . Wa halves, fused degree
// count (625 blocks x 256 threads == 160000 == E).
__global__ __launch_bounds__(256) void k_gemm_h(
    const float* __restrict__ nf, const __bf16* __restrict__ Btg,
    const float* __restrict__ bt, const float* __restrict__ Wa,
    const int* __restrict__ eidx, int* __restrict__ deg,
    __bf16* __restrict__ hs, float* __restrict__ p, float* __restrict__ q) {
  // fused degree count: one edge per thread
  {
    int e = blockIdx.x * 256 + threadIdx.x;  // < 160000 exactly
    atomicAdd(&deg[eidx[2 * e]], 1);
  }
  __shared__ __bf16 Bt[32 * 512];  // 32 KB
  const int tid = threadIdx.x;
  {
    uint4* d = (uint4*)Bt;
    const uint4* s = (const uint4*)Btg;
#pragma unroll
    for (int i = tid; i < 2048; i += 256) d[i] = s[i];
  }
  __syncthreads();

  const int wid = tid >> 6, lane = tid & 63;
  const int lr = lane & 15, lg = lane >> 4;
  const int row0 = blockIdx.x * 64 + wid * 16;

  f32x4 acc[8];
#pragma unroll
  for (int c = 0; c < 8; ++c)
#pragma unroll
    for (int r = 0; r < 4; ++r) acc[c][r] = 0.f;

#pragma unroll
  for (int k0 = 0; k0 < 128; k0 += 32) {
    int kk = k0 + lg * 8;
    const float4* ap = (const float4*)(nf + (size_t)(row0 + lr) * 128 + kk);
    float4 a0 = ap[0], a1 = ap[1];
    bf16x8 af;
    af[0] = (__bf16)a0.x; af[1] = (__bf16)a0.y; af[2] = (__bf16)a0.z; af[3] = (__bf16)a0.w;
    af[4] = (__bf16)a1.x; af[5] = (__bf16)a1.y; af[6] = (__bf16)a1.z; af[7] = (__bf16)a1.w;
#pragma unroll
    for (int c = 0; c < 8; ++c) {
      bf16x8 bf = *(const bf16x8*)(Bt + (((k0 >> 5) << 3) + c) * 512 + lane * 8);
      acc[c] = __builtin_amdgcn_mfma_f32_16x16x32_bf16(af, bf, acc[c], 0, 0, 0);
    }
  }

  float pr[4] = {0.f, 0.f, 0.f, 0.f};
  float qr[4] = {0.f, 0.f, 0.f, 0.f};
#pragma unroll
  for (int c = 0; c < 8; ++c) {
    int col = c * 16 + lr;
    float bias = bt[col];
    float walo = Wa[col], wahi = Wa[128 + col];
#pragma unroll
    for (int r = 0; r < 4; ++r) {
      float v = acc[c][r] + bias;
      v = fmaxf(v, 0.f);
      int row = row0 + lg * 4 + r;
      hs[(size_t)row * 256 + col] = (__bf16)v;  // h goes in low half of hs row
      pr[r] += v * walo;
      qr[r] += v * wahi;
    }
  }
#pragma unroll
  for (int r = 0; r < 4; ++r) {
    float pv = pr[r], qv = qr[r];
#pragma unroll
    for (int m = 1; m < 16; m <<= 1) {
      pv += __shfl_xor(pv, m);
      qv += __shfl_xor(qv, m);
    }
    if (lr == 0) {
      int row = row0 + lg * 4 + r;
      p[row] = pv;
      q[row] = qv;
    }
  }
}

// ---------------------------------------------------------------------------
// k_scan: exclusive scan of deg[10000] -> offs, cursor. One block, shfl scan.
__global__ __launch_bounds__(1024) void k_scan(const int* __restrict__ deg,
                                               int* __restrict__ offs,
                                               int* __restrict__ cursor) {
  const int t = threadIdx.x, lane = t & 63, wv = t >> 6;
  const int base = t * 10;
  int local[10];
  int s = 0;
#pragma unroll
  for (int i = 0; i < 10; ++i) {
    int v = (base + i < NN) ? deg[base + i] : 0;
    local[i] = s;
    s += v;
  }
  const int tsum = s;
#pragma unroll
  for (int off = 1; off < 64; off <<= 1) {
    int v = __shfl_up(s, off);
    if (lane >= off) s += v;
  }
  __shared__ int wsum[16];
  if (lane == 63) wsum[wv] = s;
  __syncthreads();
  int add = 0;
#pragma unroll
  for (int w = 0; w < 16; ++w) {
    int v = wsum[w];
    if (w < wv) add += v;
  }
  int pre = add + s - tsum;
#pragma unroll
  for (int i = 0; i < 10; ++i) {
    int idx = base + i;
    if (idx < NN) {
      int o = pre + local[i];
      offs[idx] = o;
      cursor[idx] = o;
    }
  }
  if (t == 1023) offs[NN] = pre + tsum;  // == EE
}

// ---------------------------------------------------------------------------
// k_att: ex[b*E+e] = exp(tanh(p[b,src]+q[b,tgt]+b_a)); global sum -> S.
// Fused CSR fill on the b==0 thread range (tid < E).
__global__ __launch_bounds__(256) void k_att(const int* __restrict__ eidx,
                                             const float* __restrict__ p,
                                             const float* __restrict__ q,
                                             const float* __restrict__ ba,
                                             int* __restrict__ cursor,
                                             int* __restrict__ elist,
                                             float* __restrict__ ex,
                                             float* __restrict__ S) {
  int tid = blockIdx.x * 256 + threadIdx.x;  // < B*E = 640000 exactly
  int b = tid / EE;
  int e = tid - b * EE;
  int s = eidx[2 * e], t = eidx[2 * e + 1];
  if (b == 0) {  // fused CSR fill
    int pos = atomicAdd(&cursor[s], 1);
    elist[pos] = e;
  }
  float a = p[b * NN + s] + q[b * NN + t] + ba[0];
  float v = __expf(tanhf(a));
  ex[tid] = v;
  float vs = v;
#pragma unroll
  for (int m = 1; m < 64; m <<= 1) vs += __shfl_xor(vs, m);
  __shared__ float part[4];
  int wid = threadIdx.x >> 6, lane = threadIdx.x & 63;
  if (lane == 0) part[wid] = vs;
  __syncthreads();
  if (threadIdx.x == 0) atomicAdd(S, part[0] + part[1] + part[2] + part[3]);
}

// ---------------------------------------------------------------------------
// k_agg: one wave per NODE, all 4 batches together (4 independent loads/edge),
// edges unrolled x2 -> 8 loads in flight per wave. Lane covers 2 units via
// packed bf16x2. scat half of hs row written at [128,256).
__global__ __launch_bounds__(256) void k_agg(
    const int* __restrict__ eidx, const int* __restrict__ elist,
    const int* __restrict__ offs, const float* __restrict__ ex,
    const float* __restrict__ S, __bf16* __restrict__ hs) {
  const int wid = threadIdx.x >> 6, lane = threadIdx.x & 63;
  const int n = blockIdx.x * 4 + wid;  // < 10000 exactly (2500 blocks)
  const int o0 = offs[n], o1 = offs[n + 1];
  const unsigned* __restrict__ hu = (const unsigned*)hs;  // 128 uints per row
  float ax0 = 0, ay0 = 0, ax1 = 0, ay1 = 0;
  float ax2 = 0, ay2 = 0, ax3 = 0, ay3 = 0;
  for (int base = o0; base < o1; base += 64) {
    int il = base + lane;
    int t_l = 0;
    float w0 = 0.f, w1 = 0.f, w2 = 0.f, w3 = 0.f;
    if (il < o1) {
      int e = elist[il];
      t_l = eidx[2 * e + 1];
      w0 = ex[e];
      w1 = ex[EE + e];
      w2 = ex[2 * EE + e];
      w3 = ex[3 * EE + e];
    }
    int cnt = min(64, o1 - base);
    for (int j = 0; j < cnt; j += 2) {
      // lane j+1 (<=63) holds zero weights if j+1 >= cnt -> no guard needed
      int ta = __shfl(t_l, j), tb = __shfl(t_l, j + 1);
      float a0 = __shfl(w0, j), a1 = __shfl(w1, j);
      float a2 = __shfl(w2, j), a3 = __shfl(w3, j);
      float b0 = __shfl(w0, j + 1), b1 = __shfl(w1, j + 1);
      float b2 = __shfl(w2, j + 1), b3 = __shfl(w3, j + 1);
      const unsigned* ra = hu + ta * 128 + lane;
      const unsigned* rb = hu + tb * 128 + lane;
      unsigned va0 = ra[0];
      unsigned va1 = ra[NN * 128];
      unsigned va2 = ra[2 * NN * 128];
      unsigned va3 = ra[3 * NN * 128];
      unsigned vb0 = rb[0];
      unsigned vb1 = rb[NN * 128];
      unsigned vb2 = rb[2 * NN * 128];
      unsigned vb3 = rb[3 * NN * 128];
#define LO(x) __uint_as_float((x) << 16)
#define HI(x) __uint_as_float((x)&0xffff0000u)
      ax0 = fmaf(a0, LO(va0), ax0); ay0 = fmaf(a0, HI(va0), ay0);
      ax1 = fmaf(a1, LO(va1), ax1); ay1 = fmaf(a1, HI(va1), ay1);
      ax2 = fmaf(a2, LO(va2), ax2); ay2 = fmaf(a2, HI(va2), ay2);
      ax3 = fmaf(a3, LO(va3), ax3); ay3 = fmaf(a3, HI(va3), ay3);
      ax0 = fmaf(b0, LO(vb0), ax0); ay0 = fmaf(b0, HI(vb0), ay0);
      ax1 = fmaf(b1, LO(vb1), ax1); ay1 = fmaf(b1, HI(vb1), ay1);
      ax2 = fmaf(b2, LO(vb2), ax2); ay2 = fmaf(b2, HI(vb2), ay2);
      ax3 = fmaf(b3, LO(vb3), ax3); ay3 = fmaf(b3, HI(vb3), ay3);
#undef LO
#undef HI
    }
  }
  const float invS = 1.0f / S[0];
  unsigned* su = (unsigned*)hs;
#define PACK(x, y, dst)                                             \
  {                                                                 \
    unsigned ux = __float_as_uint((x)*invS);                        \
    ux = (ux + 0x7fffu + ((ux >> 16) & 1u)) >> 16;                  \
    unsigned uy = __float_as_uint((y)*invS);                        \
    uy = (uy + 0x7fffu + ((uy >> 16) & 1u)) >> 16;                  \
    (dst) = ux | (uy << 16);                                        \
  }
  PACK(ax0, ay0, su[(size_t)(0 * NN + n) * 128 + 64 + lane]);
  PACK(ax1, ay1, su[(size_t)(1 * NN + n) * 128 + 64 + lane]);
  PACK(ax2, ay2, su[(size_t)(2 * NN + n) * 128 + 64 + lane]);
  PACK(ax3, ay3, su[(size_t)(3 * NN + n) * 128 + 64 + lane]);
#undef PACK
}

// ---------------------------------------------------------------------------
// GEMM2: out = relu(hs @ W_c + b_c)  (M=40000, K=256, N=128)
__global__ __launch_bounds__(256) void k_gemm_out(
    const __bf16* __restrict__ hs, const __bf16* __restrict__ Bcg,
    const float* __restrict__ bc, float* __restrict__ out) {
  __shared__ __bf16 Bt[64 * 512];  // 64 KB
  const int tid = threadIdx.x;
  {
    uint4* d = (uint4*)Bt;
    const uint4* s = (const uint4*)Bcg;
#pragma unroll
    for (int i = tid; i < 4096; i += 256) d[i] = s[i];
  }
  __syncthreads();

  const int wid = tid >> 6, lane = tid & 63;
  const int lr = lane & 15, lg = lane >> 4;
  const int row0 = blockIdx.x * 64 + wid * 16;

  f32x4 acc[8];
#pragma unroll
  for (int c = 0; c < 8; ++c)
#pragma unroll
    for (int r = 0; r < 4; ++r) acc[c][r] = 0.f;

#pragma unroll
  for (int k0 = 0; k0 < 256; k0 += 32) {
    int kk = k0 + lg * 8;
    bf16x8 af = *(const bf16x8*)(hs + (size_t)(row0 + lr) * 256 + kk);
#pragma unroll
    for (int c = 0; c < 8; ++c) {
      bf16x8 bf = *(const bf16x8*)(Bt + (((k0 >> 5) << 3) + c) * 512 + lane * 8);
      acc[c] = __builtin_amdgcn_mfma_f32_16x16x32_bf16(af, bf, acc[c], 0, 0, 0);
    }
  }

#pragma unroll
  for (int c = 0; c < 8; ++c) {
    int col = c * 16 + lr;
    float bias = bc[col];
#pragma unroll
    for (int r = 0; r < 4; ++r) {
      float v = acc[c][r] + bias;
      v = fmaxf(v, 0.f);
      int row = row0 + lg * 4 + r;
      out[(size_t)row * 128 + col] = v;
    }
  }
}

// ---------------------------------------------------------------------------
extern "C" void kernel_launch(void* const* d_in, const int* in_sizes, int n_in,
                              void* d_out, int out_size, void* d_ws,
                              size_t ws_size, hipStream_t stream) {
  const float* nf = (const float*)d_in[0];
  const int* eidx = (const int*)d_in[1];
  const float* Wt = (const float*)d_in[2];
  const float* bt = (const float*)d_in[3];
  const float* Wa = (const float*)d_in[4];
  const float* ba = (const float*)d_in[5];
  const float* Wc = (const float*)d_in[6];
  const float* bc = (const float*)d_in[7];
  float* out = (float*)d_out;

  char* w = (char*)d_ws;
  float* S = (float*)(w + WS_S);
  int* deg = (int*)(w + WS_DEG);
  int* offs = (int*)(w + WS_OFFS);
  int* cursor = (int*)(w + WS_CUR);
  int* elist = (int*)(w + WS_ELIST);
  float* p = (float*)(w + WS_P);
  float* q = (float*)(w + WS_Q);
  float* ex = (float*)(w + WS_EX);
  __bf16* Btg = (__bf16*)(w + WS_BTG);
  __bf16* Bcg = (__bf16*)(w + WS_BCG);
  __bf16* hs = (__bf16*)(w + WS_HS);

  k_prep<<<8, 256, 0, stream>>>(Wt, Wc, w);
  k_gemm_h<<<625, 256, 0, stream>>>(nf, Btg, bt, Wa, eidx, deg, hs, p, q);
  k_scan<<<1, 1024, 0, stream>>>(deg, offs, cursor);
  k_att<<<2500, 256, 0, stream>>>(eidx, p, q, ba, cursor, elist, ex, S);
  k_agg<<<2500, 256, 0, stream>>>(eidx, elist, offs, ex, S, hs);
  k_gemm_out<<<625, 256, 0, stream>>>(hs, Bcg, bc, out);
}

// Round 3
// 194.926 us; speedup vs baseline: 1.2156x; 1.0196x over previous
//
#include <hip/hip_runtime.h>

// Problem constants (match reference setup_inputs)
#define BB 4
#define NN 10000
#define FF 128
#define UU 128
#define EE 160000

typedef __bf16 bf16x8 __attribute__((ext_vector_type(8)));
typedef float  f32x4  __attribute__((ext_vector_type(4)));

// ws layout (bytes)
#define WS_S      0         // float S (4 B)
#define WS_DEG    256       // int[10000]
#define WS_OFFS   40448     // int[10001]
#define WS_CUR    80640     // int[10000]
#define WS_ELIST  120832    // int[160000]
#define WS_P      760832    // float[40000]
#define WS_Q      920832    // float[40000]
#define WS_EX     1080832   // float[640000]
#define WS_BTG    3640832   // bf16 swizzled W_t (32 KB)
#define WS_BCG    3673600   // bf16 swizzled W_c (64 KB)
#define WS_HS     3739136   // bf16 hs[40000][256]  (h | scat interleaved)

// ---------------------------------------------------------------------------
// k_prep: zero S+deg; pre-swizzle W_t and W_c into bf16 MFMA-frag layout.
__global__ __launch_bounds__(256) void k_prep(const float* __restrict__ Wt,
                                              const float* __restrict__ Wc,
                                              char* __restrict__ ws) {
  const int gid = blockIdx.x * 256 + threadIdx.x;  // 8 blocks -> 2048 threads
  uint4* zp = (uint4*)ws;
  uint4 z = {0u, 0u, 0u, 0u};
  for (int i = gid; i < 2528; i += 2048) zp[i] = z;

  __bf16* Btg = (__bf16*)(ws + WS_BTG);
  __bf16* Bcg = (__bf16*)(ws + WS_BCG);
  {
    int i = gid;
    int n = i & 127, kb8 = i >> 7;  // kb8 in [0,16)
    int kc = kb8 >> 2, kbq = kb8 & 3;
    int lane = (n & 15) | (kbq << 4), c = n >> 4;
    const float* src = Wt + (size_t)kb8 * 8 * 128 + n;
    bf16x8 v;
#pragma unroll
    for (int j = 0; j < 8; ++j) v[j] = (__bf16)src[(size_t)j * 128];
    *(bf16x8*)(Btg + ((kc * 8 + c) * 512 + lane * 8)) = v;
  }
#pragma unroll
  for (int it = 0; it < 2; ++it) {
    int i = gid + it * 2048;
    int n = i & 127, kb8 = i >> 7;  // kb8 in [0,32)
    int kc = kb8 >> 2, kbq = kb8 & 3;
    int lane = (n & 15) | (kbq << 4), c = n >> 4;
    const float* src = Wc + (size_t)kb8 * 8 * 128 + n;
    bf16x8 v;
#pragma unroll
    for (int j = 0; j < 8; ++j) v[j] = (__bf16)src[(size_t)j * 128];
    *(bf16x8*)(Bcg + ((kc * 8 + c) * 512 + lane * 8)) = v;
  }
}

// ---------------------------------------------------------------------------
// GEMM1: h = relu(nf @ W_t + b_t), fused p/q = h . Wa halves, fused degree
// count (625 blocks x 256 threads == 160000 == E).
__global__ __launch_bounds__(256) void k_gemm_h(
    const float* __restrict__ nf, const __bf16* __restrict__ Btg,
    const float* __restrict__ bt, const float* __restrict__ Wa,
    const int* __restrict__ eidx, int* __restrict__ deg,
    __bf16* __restrict__ hs, float* __restrict__ p, float* __restrict__ q) {
  {
    int e = blockIdx.x * 256 + threadIdx.x;  // < 160000 exactly
    atomicAdd(&deg[eidx[2 * e]], 1);
  }
  __shared__ __bf16 Bt[32 * 512];  // 32 KB
  const int tid = threadIdx.x;
  {
    uint4* d = (uint4*)Bt;
    const uint4* s = (const uint4*)Btg;
#pragma unroll
    for (int i = tid; i < 2048; i += 256) d[i] = s[i];
  }
  __syncthreads();

  const int wid = tid >> 6, lane = tid & 63;
  const int lr = lane & 15, lg = lane >> 4;
  const int row0 = blockIdx.x * 64 + wid * 16;

  f32x4 acc[8];
#pragma unroll
  for (int c = 0; c < 8; ++c)
#pragma unroll
    for (int r = 0; r < 4; ++r) acc[c][r] = 0.f;

#pragma unroll
  for (int k0 = 0; k0 < 128; k0 += 32) {
    int kk = k0 + lg * 8;
    const float4* ap = (const float4*)(nf + (size_t)(row0 + lr) * 128 + kk);
    float4 a0 = ap[0], a1 = ap[1];
    bf16x8 af;
    af[0] = (__bf16)a0.x; af[1] = (__bf16)a0.y; af[2] = (__bf16)a0.z; af[3] = (__bf16)a0.w;
    af[4] = (__bf16)a1.x; af[5] = (__bf16)a1.y; af[6] = (__bf16)a1.z; af[7] = (__bf16)a1.w;
#pragma unroll
    for (int c = 0; c < 8; ++c) {
      bf16x8 bf = *(const bf16x8*)(Bt + (((k0 >> 5) << 3) + c) * 512 + lane * 8);
      acc[c] = __builtin_amdgcn_mfma_f32_16x16x32_bf16(af, bf, acc[c], 0, 0, 0);
    }
  }

  float pr[4] = {0.f, 0.f, 0.f, 0.f};
  float qr[4] = {0.f, 0.f, 0.f, 0.f};
#pragma unroll
  for (int c = 0; c < 8; ++c) {
    int col = c * 16 + lr;
    float bias = bt[col];
    float walo = Wa[col], wahi = Wa[128 + col];
#pragma unroll
    for (int r = 0; r < 4; ++r) {
      float v = acc[c][r] + bias;
      v = fmaxf(v, 0.f);
      int row = row0 + lg * 4 + r;
      hs[(size_t)row * 256 + col] = (__bf16)v;
      pr[r] += v * walo;
      qr[r] += v * wahi;
    }
  }
#pragma unroll
  for (int r = 0; r < 4; ++r) {
    float pv = pr[r], qv = qr[r];
#pragma unroll
    for (int m = 1; m < 16; m <<= 1) {
      pv += __shfl_xor(pv, m);
      qv += __shfl_xor(qv, m);
    }
    if (lr == 0) {
      int row = row0 + lg * 4 + r;
      p[row] = pv;
      q[row] = qv;
    }
  }
}

// ---------------------------------------------------------------------------
// k_scan: exclusive scan of deg[10000] -> offs, cursor. One block, shfl scan.
__global__ __launch_bounds__(1024) void k_scan(const int* __restrict__ deg,
                                               int* __restrict__ offs,
                                               int* __restrict__ cursor) {
  const int t = threadIdx.x, lane = t & 63, wv = t >> 6;
  const int base = t * 10;
  int local[10];
  int s = 0;
#pragma unroll
  for (int i = 0; i < 10; ++i) {
    int v = (base + i < NN) ? deg[base + i] : 0;
    local[i] = s;
    s += v;
  }
  const int tsum = s;
#pragma unroll
  for (int off = 1; off < 64; off <<= 1) {
    int v = __shfl_up(s, off);
    if (lane >= off) s += v;
  }
  __shared__ int wsum[16];
  if (lane == 63) wsum[wv] = s;
  __syncthreads();
  int add = 0;
#pragma unroll
  for (int w = 0; w < 16; ++w) {
    int v = wsum[w];
    if (w < wv) add += v;
  }
  int pre = add + s - tsum;
#pragma unroll
  for (int i = 0; i < 10; ++i) {
    int idx = base + i;
    if (idx < NN) {
      int o = pre + local[i];
      offs[idx] = o;
      cursor[idx] = o;
    }
  }
  if (t == 1023) offs[NN] = pre + tsum;  // == EE
}

// ---------------------------------------------------------------------------
// k_att: ex = exp(tanh(p[src]+q[tgt]+ba)); global sum -> S. Fast tanh via
// exp identity: tanh(a) = 1 - 2/(e^{2a}+1)  (exact in fp32 terms, branchless;
// a->+inf gives z=inf -> t=1, a->-inf gives z=0 -> t=-1).
__global__ __launch_bounds__(256) void k_att(const int* __restrict__ eidx,
                                             const float* __restrict__ p,
                                             const float* __restrict__ q,
                                             const float* __restrict__ ba,
                                             int* __restrict__ cursor,
                                             int* __restrict__ elist,
                                             float* __restrict__ ex,
                                             float* __restrict__ S) {
  int tid = blockIdx.x * 256 + threadIdx.x;  // < B*E = 640000 exactly
  int b = tid / EE;
  int e = tid - b * EE;
  int s = eidx[2 * e], t = eidx[2 * e + 1];
  if (b == 0) {  // fused CSR fill
    int pos = atomicAdd(&cursor[s], 1);
    elist[pos] = e;
  }
  float a = p[b * NN + s] + q[b * NN + t] + ba[0];
  float z = __expf(2.f * a);
  float th = 1.f - __fdividef(2.f, z + 1.f);
  float v = __expf(th);
  ex[tid] = v;
  float vs = v;
#pragma unroll
  for (int m = 1; m < 64; m <<= 1) vs += __shfl_xor(vs, m);
  __shared__ float part[4];
  int wid = threadIdx.x >> 6, lane = threadIdx.x & 63;
  if (lane == 0) part[wid] = vs;
  __syncthreads();
  if (threadIdx.x == 0) atomicAdd(S, part[0] + part[1] + part[2] + part[3]);
}

// ---------------------------------------------------------------------------
// k_agg: one wave per NODE, all 4 batches, edges unrolled x4 -> 16 row-loads
// in flight per wave. Lanes beyond the valid count carry w=0/t=0 so no guard
// is needed inside the unrolled body.
__global__ __launch_bounds__(256) void k_agg(
    const int* __restrict__ eidx, const int* __restrict__ elist,
    const int* __restrict__ offs, const float* __restrict__ ex,
    const float* __restrict__ S, __bf16* __restrict__ hs) {
  const int wid = threadIdx.x >> 6, lane = threadIdx.x & 63;
  const int n = blockIdx.x * 4 + wid;  // < 10000 exactly (2500 blocks)
  const int o0 = offs[n], o1 = offs[n + 1];
  const unsigned* __restrict__ hu = (const unsigned*)hs;  // 128 uints per row
  float ax[4] = {0.f, 0.f, 0.f, 0.f};
  float ay[4] = {0.f, 0.f, 0.f, 0.f};
  for (int base = o0; base < o1; base += 64) {
    int il = base + lane;
    int t_l = 0;
    float w0 = 0.f, w1 = 0.f, w2 = 0.f, w3 = 0.f;
    if (il < o1) {
      int e = elist[il];
      t_l = eidx[2 * e + 1];
      w0 = ex[e];
      w1 = ex[EE + e];
      w2 = ex[2 * EE + e];
      w3 = ex[3 * EE + e];
    }
    int cnt = min(64, o1 - base);
    for (int j = 0; j < cnt; j += 4) {
      int t0 = __shfl(t_l, j + 0);
      int t1 = __shfl(t_l, j + 1);
      int t2 = __shfl(t_l, j + 2);
      int t3 = __shfl(t_l, j + 3);
      const unsigned* r0 = hu + t0 * 128 + lane;
      const unsigned* r1 = hu + t1 * 128 + lane;
      const unsigned* r2 = hu + t2 * 128 + lane;
      const unsigned* r3 = hu + t3 * 128 + lane;
      unsigned v0[4], v1[4], v2[4], v3[4];
#pragma unroll
      for (int b = 0; b < 4; ++b) v0[b] = r0[(size_t)b * NN * 128];
#pragma unroll
      for (int b = 0; b < 4; ++b) v1[b] = r1[(size_t)b * NN * 128];
#pragma unroll
      for (int b = 0; b < 4; ++b) v2[b] = r2[(size_t)b * NN * 128];
#pragma unroll
      for (int b = 0; b < 4; ++b) v3[b] = r3[(size_t)b * NN * 128];
      float e0w[4] = {__shfl(w0, j + 0), __shfl(w1, j + 0), __shfl(w2, j + 0), __shfl(w3, j + 0)};
      float e1w[4] = {__shfl(w0, j + 1), __shfl(w1, j + 1), __shfl(w2, j + 1), __shfl(w3, j + 1)};
      float e2w[4] = {__shfl(w0, j + 2), __shfl(w1, j + 2), __shfl(w2, j + 2), __shfl(w3, j + 2)};
      float e3w[4] = {__shfl(w0, j + 3), __shfl(w1, j + 3), __shfl(w2, j + 3), __shfl(w3, j + 3)};
#define LO(x) __uint_as_float((x) << 16)
#define HI(x) __uint_as_float((x)&0xffff0000u)
#pragma unroll
      for (int b = 0; b < 4; ++b) {
        ax[b] = fmaf(e0w[b], LO(v0[b]), ax[b]);
        ay[b] = fmaf(e0w[b], HI(v0[b]), ay[b]);
        ax[b] = fmaf(e1w[b], LO(v1[b]), ax[b]);
        ay[b] = fmaf(e1w[b], HI(v1[b]), ay[b]);
        ax[b] = fmaf(e2w[b], LO(v2[b]), ax[b]);
        ay[b] = fmaf(e2w[b], HI(v2[b]), ay[b]);
        ax[b] = fmaf(e3w[b], LO(v3[b]), ax[b]);
        ay[b] = fmaf(e3w[b], HI(v3[b]), ay[b]);
      }
#undef LO
#undef HI
    }
  }
  const float invS = 1.0f / S[0];
  unsigned* su = (unsigned*)hs;
#pragma unroll
  for (int b = 0; b < 4; ++b) {
    unsigned ux = __float_as_uint(ax[b] * invS);
    ux = (ux + 0x7fffu + ((ux >> 16) & 1u)) >> 16;
    unsigned uy = __float_as_uint(ay[b] * invS);
    uy = (uy + 0x7fffu + ((uy >> 16) & 1u)) >> 16;
    su[(size_t)(b * NN + n) * 128 + 64 + lane] = ux | (uy << 16);
  }
}

// ---------------------------------------------------------------------------
// GEMM2: out = relu(hs @ W_c + b_c)  (M=40000, K=256, N=128)
// 128 rows/block (32 rows/wave, two 16-row tiles) -> halves B-staging traffic.
__global__ __launch_bounds__(256) void k_gemm_out(
    const __bf16* __restrict__ hs, const __bf16* __restrict__ Bcg,
    const float* __restrict__ bc, float* __restrict__ out) {
  __shared__ __bf16 Bt[64 * 512];  // 64 KB
  const int tid = threadIdx.x;
  {
    uint4* d = (uint4*)Bt;
    const uint4* s = (const uint4*)Bcg;
#pragma unroll
    for (int i = tid; i < 4096; i += 256) d[i] = s[i];
  }
  __syncthreads();

  const int wid = tid >> 6, lane = tid & 63;
  const int lr = lane & 15, lg = lane >> 4;
  const int row0 = blockIdx.x * 128 + wid * 32;  // two 16-row tiles per wave

  f32x4 acc[2][8];
#pragma unroll
  for (int t = 0; t < 2; ++t)
#pragma unroll
    for (int c = 0; c < 8; ++c)
#pragma unroll
      for (int r = 0; r < 4; ++r) acc[t][c][r] = 0.f;

  int ra = row0 + lr;
  int rb = row0 + 16 + lr;
  ra = min(ra, 39999);  // tail-block clamp (loads only; stores are guarded)
  rb = min(rb, 39999);

#pragma unroll
  for (int k0 = 0; k0 < 256; k0 += 32) {
    int kk = k0 + lg * 8;
    bf16x8 af0 = *(const bf16x8*)(hs + (size_t)ra * 256 + kk);
    bf16x8 af1 = *(const bf16x8*)(hs + (size_t)rb * 256 + kk);
#pragma unroll
    for (int c = 0; c < 8; ++c) {
      bf16x8 bf = *(const bf16x8*)(Bt + (((k0 >> 5) << 3) + c) * 512 + lane * 8);
      acc[0][c] = __builtin_amdgcn_mfma_f32_16x16x32_bf16(af0, bf, acc[0][c], 0, 0, 0);
      acc[1][c] = __builtin_amdgcn_mfma_f32_16x16x32_bf16(af1, bf, acc[1][c], 0, 0, 0);
    }
  }

#pragma unroll
  for (int t = 0; t < 2; ++t)
#pragma unroll
    for (int c = 0; c < 8; ++c) {
      int col = c * 16 + lr;
      float bias = bc[col];
#pragma unroll
      for (int r = 0; r < 4; ++r) {
        float v = acc[t][c][r] + bias;
        v = fmaxf(v, 0.f);
        int row = row0 + t * 16 + lg * 4 + r;
        if (row < 40000) out[(size_t)row * 128 + col] = v;
      }
    }
}

// ---------------------------------------------------------------------------
extern "C" void kernel_launch(void* const* d_in, const int* in_sizes, int n_in,
                              void* d_out, int out_size, void* d_ws,
                              size_t ws_size, hipStream_t stream) {
  const float* nf = (const float*)d_in[0];
  const int* eidx = (const int*)d_in[1];
  const float* Wt = (const float*)d_in[2];
  const float* bt = (const float*)d_in[3];
  const float* Wa = (const float*)d_in[4];
  const float* ba = (const float*)d_in[5];
  const float* Wc = (const float*)d_in[6];
  const float* bc = (const float*)d_in[7];
  float* out = (float*)d_out;

  char* w = (char*)d_ws;
  float* S = (float*)(w + WS_S);
  int* deg = (int*)(w + WS_DEG);
  int* offs = (int*)(w + WS_OFFS);
  int* cursor = (int*)(w + WS_CUR);
  int* elist = (int*)(w + WS_ELIST);
  float* p = (float*)(w + WS_P);
  float* q = (float*)(w + WS_Q);
  float* ex = (float*)(w + WS_EX);
  __bf16* Btg = (__bf16*)(w + WS_BTG);
  __bf16* Bcg = (__bf16*)(w + WS_BCG);
  __bf16* hs = (__bf16*)(w + WS_HS);

  k_prep<<<8, 256, 0, stream>>>(Wt, Wc, w);
  k_gemm_h<<<625, 256, 0, stream>>>(nf, Btg, bt, Wa, eidx, deg, hs, p, q);
  k_scan<<<1, 1024, 0, stream>>>(deg, offs, cursor);
  k_att<<<2500, 256, 0, stream>>>(eidx, p, q, ba, cursor, elist, ex, S);
  k_agg<<<2500, 256, 0, stream>>>(eidx, elist, offs, ex, S, hs);
  k_gemm_out<<<313, 256, 0, stream>>>(hs, Bcg, bc, out);
}

// Round 4
// 164.472 us; speedup vs baseline: 1.4406x; 1.1852x over previous
//
#include <hip/hip_runtime.h>

// Problem constants (match reference setup_inputs)
#define BB 4
#define NN 10000
#define FF 128
#define UU 128
#define EE 160000

typedef __bf16 bf16x8 __attribute__((ext_vector_type(8)));
typedef float  f32x4  __attribute__((ext_vector_type(4)));

// ws layout (bytes)
#define WS_S      0         // float S (4 B)
#define WS_DEG    256       // int[10000]
#define WS_OFFS   40448     // int[10001]
#define WS_CUR    80640     // int[10000]
#define WS_TGT    120832    // int[160000]            (CSR-ordered tgt)
#define WS_EXW    760832    // float4[160000]         (CSR-ordered weights)
#define WS_P      3320832   // float[40000]  p2[n][b] (node-major float4)
#define WS_Q      3480832   // float[40000]  q2[n][b]
#define WS_BTG    3640832   // bf16 swizzled W_t (32 KB)
#define WS_BCG    3673600   // bf16 swizzled W_c (64 KB)
#define WS_HS     3739136   // bf16 hs2[10000][4][256] (h | scat interleaved)

// ---------------------------------------------------------------------------
// k_prep: zero S+deg; pre-swizzle W_t and W_c into bf16 MFMA-frag layout.
__global__ __launch_bounds__(256) void k_prep(const float* __restrict__ Wt,
                                              const float* __restrict__ Wc,
                                              char* __restrict__ ws) {
  const int gid = blockIdx.x * 256 + threadIdx.x;  // 8 blocks -> 2048 threads
  uint4* zp = (uint4*)ws;
  uint4 z = {0u, 0u, 0u, 0u};
  for (int i = gid; i < 2528; i += 2048) zp[i] = z;

  __bf16* Btg = (__bf16*)(ws + WS_BTG);
  __bf16* Bcg = (__bf16*)(ws + WS_BCG);
  {
    int i = gid;
    int n = i & 127, kb8 = i >> 7;  // kb8 in [0,16)
    int kc = kb8 >> 2, kbq = kb8 & 3;
    int lane = (n & 15) | (kbq << 4), c = n >> 4;
    const float* src = Wt + (size_t)kb8 * 8 * 128 + n;
    bf16x8 v;
#pragma unroll
    for (int j = 0; j < 8; ++j) v[j] = (__bf16)src[(size_t)j * 128];
    *(bf16x8*)(Btg + ((kc * 8 + c) * 512 + lane * 8)) = v;
  }
#pragma unroll
  for (int it = 0; it < 2; ++it) {
    int i = gid + it * 2048;
    int n = i & 127, kb8 = i >> 7;  // kb8 in [0,32)
    int kc = kb8 >> 2, kbq = kb8 & 3;
    int lane = (n & 15) | (kbq << 4), c = n >> 4;
    const float* src = Wc + (size_t)kb8 * 8 * 128 + n;
    bf16x8 v;
#pragma unroll
    for (int j = 0; j < 8; ++j) v[j] = (__bf16)src[(size_t)j * 128];
    *(bf16x8*)(Bcg + ((kc * 8 + c) * 512 + lane * 8)) = v;
  }
}

// ---------------------------------------------------------------------------
// GEMM1: h = relu(nf @ W_t + b_t) -> hs2[n][b][0:128]; fused p2/q2 and degree
// count. Rows are m = b*NN+n (nf layout); hs2 row index is n*4+b.
__global__ __launch_bounds__(256) void k_gemm_h(
    const float* __restrict__ nf, const __bf16* __restrict__ Btg,
    const float* __restrict__ bt, const float* __restrict__ Wa,
    const int* __restrict__ eidx, int* __restrict__ deg,
    __bf16* __restrict__ hs, float* __restrict__ p2, float* __restrict__ q2) {
  {
    int e = blockIdx.x * 256 + threadIdx.x;  // < 160000 exactly
    atomicAdd(&deg[eidx[2 * e]], 1);
  }
  __shared__ __bf16 Bt[32 * 512];  // 32 KB
  const int tid = threadIdx.x;
  {
    uint4* d = (uint4*)Bt;
    const uint4* s = (const uint4*)Btg;
#pragma unroll
    for (int i = tid; i < 2048; i += 256) d[i] = s[i];
  }
  __syncthreads();

  const int wid = tid >> 6, lane = tid & 63;
  const int lr = lane & 15, lg = lane >> 4;
  const int row0 = blockIdx.x * 64 + wid * 16;

  f32x4 acc[8];
#pragma unroll
  for (int c = 0; c < 8; ++c)
#pragma unroll
    for (int r = 0; r < 4; ++r) acc[c][r] = 0.f;

#pragma unroll
  for (int k0 = 0; k0 < 128; k0 += 32) {
    int kk = k0 + lg * 8;
    const float4* ap = (const float4*)(nf + (size_t)(row0 + lr) * 128 + kk);
    float4 a0 = ap[0], a1 = ap[1];
    bf16x8 af;
    af[0] = (__bf16)a0.x; af[1] = (__bf16)a0.y; af[2] = (__bf16)a0.z; af[3] = (__bf16)a0.w;
    af[4] = (__bf16)a1.x; af[5] = (__bf16)a1.y; af[6] = (__bf16)a1.z; af[7] = (__bf16)a1.w;
#pragma unroll
    for (int c = 0; c < 8; ++c) {
      bf16x8 bf = *(const bf16x8*)(Bt + (((k0 >> 5) << 3) + c) * 512 + lane * 8);
      acc[c] = __builtin_amdgcn_mfma_f32_16x16x32_bf16(af, bf, acc[c], 0, 0, 0);
    }
  }

#pragma unroll
  for (int r = 0; r < 4; ++r) {
    int row = row0 + lg * 4 + r;         // m = b*NN + n
    int b = row / NN;
    int n = row - b * NN;
    size_t dst = ((size_t)n * 4 + b) * 256;  // hs2 row
    float pr = 0.f, qr = 0.f;
#pragma unroll
    for (int c = 0; c < 8; ++c) {
      int col = c * 16 + lr;
      float v = acc[c][r] + bt[col];
      v = fmaxf(v, 0.f);
      hs[dst + col] = (__bf16)v;
      pr += v * Wa[col];
      qr += v * Wa[128 + col];
    }
#pragma unroll
    for (int m = 1; m < 16; m <<= 1) {
      pr += __shfl_xor(pr, m);
      qr += __shfl_xor(qr, m);
    }
    if (lr == 0) {
      p2[n * 4 + b] = pr;
      q2[n * 4 + b] = qr;
    }
  }
}

// ---------------------------------------------------------------------------
// k_scan: exclusive scan of deg[10000] -> offs, cursor. One block, shfl scan.
__global__ __launch_bounds__(1024) void k_scan(const int* __restrict__ deg,
                                               int* __restrict__ offs,
                                               int* __restrict__ cursor) {
  const int t = threadIdx.x, lane = t & 63, wv = t >> 6;
  const int base = t * 10;
  int local[10];
  int s = 0;
#pragma unroll
  for (int i = 0; i < 10; ++i) {
    int v = (base + i < NN) ? deg[base + i] : 0;
    local[i] = s;
    s += v;
  }
  const int tsum = s;
#pragma unroll
  for (int off = 1; off < 64; off <<= 1) {
    int v = __shfl_up(s, off);
    if (lane >= off) s += v;
  }
  __shared__ int wsum[16];
  if (lane == 63) wsum[wv] = s;
  __syncthreads();
  int add = 0;
#pragma unroll
  for (int w = 0; w < 16; ++w) {
    int v = wsum[w];
    if (w < wv) add += v;
  }
  int pre = add + s - tsum;
#pragma unroll
  for (int i = 0; i < 10; ++i) {
    int idx = base + i;
    if (idx < NN) {
      int o = pre + local[i];
      offs[idx] = o;
      cursor[idx] = o;
    }
  }
  if (t == 1023) offs[NN] = pre + tsum;  // == EE
}

// ---------------------------------------------------------------------------
// k_att: one thread per EDGE. Computes all 4 batches' exp(tanh(...)), claims
// the CSR slot, writes tgts[pos] + exw[pos] (float4, CSR-ordered), and
// accumulates the global softmax denominator S.
__global__ __launch_bounds__(256) void k_att(const int* __restrict__ eidx,
                                             const float4* __restrict__ p2,
                                             const float4* __restrict__ q2,
                                             const float* __restrict__ ba,
                                             int* __restrict__ cursor,
                                             int* __restrict__ tgts,
                                             float4* __restrict__ exw,
                                             float* __restrict__ S) {
  int e = blockIdx.x * 256 + threadIdx.x;  // < 160000 exactly
  int s = eidx[2 * e], t = eidx[2 * e + 1];
  float4 pv = p2[s];
  float4 qv = q2[t];
  float bias = ba[0];
  // tanh(a) = 1 - 2/(e^{2a}+1), then exp(.)
#define ATT(pc, qc, out)                              \
  {                                                   \
    float a = (pc) + (qc) + bias;                     \
    float z = __expf(2.f * a);                        \
    float th = 1.f - __fdividef(2.f, z + 1.f);        \
    (out) = __expf(th);                               \
  }
  float v0, v1, v2, v3;
  ATT(pv.x, qv.x, v0)
  ATT(pv.y, qv.y, v1)
  ATT(pv.z, qv.z, v2)
  ATT(pv.w, qv.w, v3)
#undef ATT
  int pos = atomicAdd(&cursor[s], 1);
  tgts[pos] = t;
  exw[pos] = make_float4(v0, v1, v2, v3);
  float vs = v0 + v1 + v2 + v3;
#pragma unroll
  for (int m = 1; m < 64; m <<= 1) vs += __shfl_xor(vs, m);
  __shared__ float part[4];
  int wid = threadIdx.x >> 6, lane = threadIdx.x & 63;
  if (lane == 0) part[wid] = vs;
  __syncthreads();
  if (threadIdx.x == 0) atomicAdd(S, part[0] + part[1] + part[2] + part[3]);
}

// ---------------------------------------------------------------------------
// k_agg: one wave per node. Per edge: ONE dwordx4/lane covers the node's
// entire 4-batch h gather (lane = batch l>>4, cols 8*(l&15)..+7). tgts/exw
// are CSR-ordered -> coalesced meta loads. Edges unrolled x2.
__global__ __launch_bounds__(256) void k_agg(
    const int* __restrict__ tgts, const int* __restrict__ offs,
    const float4* __restrict__ exw, const float* __restrict__ S,
    __bf16* __restrict__ hs) {
  const int wid = threadIdx.x >> 6, lane = threadIdx.x & 63;
  const int n = blockIdx.x * 4 + wid;  // < 10000 exactly (2500 blocks)
  const int myb = lane >> 4, sub = lane & 15;
  const int o0 = offs[n], o1 = offs[n + 1];
  const uint4* __restrict__ hu4 = (const uint4*)hs;  // 128 uint4 per node
  float acc[8];
#pragma unroll
  for (int i = 0; i < 8; ++i) acc[i] = 0.f;

  const int lbase = myb * 32 + sub;  // lane's uint4 slot within a node's h half
  for (int base = o0; base < o1; base += 64) {
    int il = base + lane;
    int t_l = 0;
    float4 wv = {0.f, 0.f, 0.f, 0.f};
    if (il < o1) {
      t_l = tgts[il];
      wv = exw[il];
    }
    int cnt = min(64, o1 - base);
    for (int j = 0; j < cnt; j += 2) {
      int t0 = __shfl(t_l, j), t1 = __shfl(t_l, j + 1);
      float w0x = __shfl(wv.x, j), w0y = __shfl(wv.y, j);
      float w0z = __shfl(wv.z, j), w0w = __shfl(wv.w, j);
      float w1x = __shfl(wv.x, j + 1), w1y = __shfl(wv.y, j + 1);
      float w1z = __shfl(wv.z, j + 1), w1w = __shfl(wv.w, j + 1);
      uint4 va = hu4[(size_t)t0 * 128 + lbase];
      uint4 vb = hu4[(size_t)t1 * 128 + lbase];
      float mw0 = (myb == 0) ? w0x : (myb == 1) ? w0y : (myb == 2) ? w0z : w0w;
      float mw1 = (myb == 0) ? w1x : (myb == 1) ? w1y : (myb == 2) ? w1z : w1w;
#define LO(x) __uint_as_float((x) << 16)
#define HI(x) __uint_as_float((x)&0xffff0000u)
      acc[0] = fmaf(mw0, LO(va.x), acc[0]); acc[1] = fmaf(mw0, HI(va.x), acc[1]);
      acc[2] = fmaf(mw0, LO(va.y), acc[2]); acc[3] = fmaf(mw0, HI(va.y), acc[3]);
      acc[4] = fmaf(mw0, LO(va.z), acc[4]); acc[5] = fmaf(mw0, HI(va.z), acc[5]);
      acc[6] = fmaf(mw0, LO(va.w), acc[6]); acc[7] = fmaf(mw0, HI(va.w), acc[7]);
      acc[0] = fmaf(mw1, LO(vb.x), acc[0]); acc[1] = fmaf(mw1, HI(vb.x), acc[1]);
      acc[2] = fmaf(mw1, LO(vb.y), acc[2]); acc[3] = fmaf(mw1, HI(vb.y), acc[3]);
      acc[4] = fmaf(mw1, LO(vb.z), acc[4]); acc[5] = fmaf(mw1, HI(vb.z), acc[5]);
      acc[6] = fmaf(mw1, LO(vb.w), acc[6]); acc[7] = fmaf(mw1, HI(vb.w), acc[7]);
#undef LO
#undef HI
    }
  }
  const float invS = 1.0f / S[0];
  uint4 st;
  unsigned* sp = (unsigned*)&st;
#pragma unroll
  for (int i = 0; i < 4; ++i) {
    unsigned ux = __float_as_uint(acc[2 * i] * invS);
    ux = (ux + 0x7fffu + ((ux >> 16) & 1u)) >> 16;
    unsigned uy = __float_as_uint(acc[2 * i + 1] * invS);
    uy = (uy + 0x7fffu + ((uy >> 16) & 1u)) >> 16;
    sp[i] = ux | (uy << 16);
  }
  ((uint4*)hs)[(size_t)n * 128 + myb * 32 + 16 + sub] = st;  // scat half
}

// ---------------------------------------------------------------------------
// GEMM2: out = relu(hs2 @ W_c + b_c)  (M=40000 rows m=n*4+b, K=256, N=128)
// 128 rows/block; epilogue maps m -> out row b*NN+n.
__global__ __launch_bounds__(256) void k_gemm_out(
    const __bf16* __restrict__ hs, const __bf16* __restrict__ Bcg,
    const float* __restrict__ bc, float* __restrict__ out) {
  __shared__ __bf16 Bt[64 * 512];  // 64 KB
  const int tid = threadIdx.x;
  {
    uint4* d = (uint4*)Bt;
    const uint4* s = (const uint4*)Bcg;
#pragma unroll
    for (int i = tid; i < 4096; i += 256) d[i] = s[i];
  }
  __syncthreads();

  const int wid = tid >> 6, lane = tid & 63;
  const int lr = lane & 15, lg = lane >> 4;
  const int row0 = blockIdx.x * 128 + wid * 32;  // two 16-row tiles per wave

  f32x4 acc[2][8];
#pragma unroll
  for (int t = 0; t < 2; ++t)
#pragma unroll
    for (int c = 0; c < 8; ++c)
#pragma unroll
      for (int r = 0; r < 4; ++r) acc[t][c][r] = 0.f;

  int ra = min(row0 + lr, 39999);
  int rb = min(row0 + 16 + lr, 39999);

#pragma unroll
  for (int k0 = 0; k0 < 256; k0 += 32) {
    int kk = k0 + lg * 8;
    bf16x8 af0 = *(const bf16x8*)(hs + (size_t)ra * 256 + kk);
    bf16x8 af1 = *(const bf16x8*)(hs + (size_t)rb * 256 + kk);
#pragma unroll
    for (int c = 0; c < 8; ++c) {
      bf16x8 bf = *(const bf16x8*)(Bt + (((k0 >> 5) << 3) + c) * 512 + lane * 8);
      acc[0][c] = __builtin_amdgcn_mfma_f32_16x16x32_bf16(af0, bf, acc[0][c], 0, 0, 0);
      acc[1][c] = __builtin_amdgcn_mfma_f32_16x16x32_bf16(af1, bf, acc[1][c], 0, 0, 0);
    }
  }

#pragma unroll
  for (int t = 0; t < 2; ++t)
#pragma unroll
    for (int r = 0; r < 4; ++r) {
      int m = row0 + t * 16 + lg * 4 + r;  // hs2 row = n*4+b
      if (m < 40000) {
        int n = m >> 2, b = m & 3;
        size_t orow = ((size_t)b * NN + n) * 128;
#pragma unroll
        for (int c = 0; c < 8; ++c) {
          int col = c * 16 + lr;
          float v = acc[t][c][r] + bc[col];
          out[orow + col] = fmaxf(v, 0.f);
        }
      }
    }
}

// ---------------------------------------------------------------------------
extern "C" void kernel_launch(void* const* d_in, const int* in_sizes, int n_in,
                              void* d_out, int out_size, void* d_ws,
                              size_t ws_size, hipStream_t stream) {
  const float* nf = (const float*)d_in[0];
  const int* eidx = (const int*)d_in[1];
  const float* Wt = (const float*)d_in[2];
  const float* bt = (const float*)d_in[3];
  const float* Wa = (const float*)d_in[4];
  const float* ba = (const float*)d_in[5];
  const float* Wc = (const float*)d_in[6];
  const float* bc = (const float*)d_in[7];
  float* out = (float*)d_out;

  char* w = (char*)d_ws;
  float* S = (float*)(w + WS_S);
  int* deg = (int*)(w + WS_DEG);
  int* offs = (int*)(w + WS_OFFS);
  int* cursor = (int*)(w + WS_CUR);
  int* tgts = (int*)(w + WS_TGT);
  float4* exw = (float4*)(w + WS_EXW);
  float* p2 = (float*)(w + WS_P);
  float* q2 = (float*)(w + WS_Q);
  __bf16* Btg = (__bf16*)(w + WS_BTG);
  __bf16* Bcg = (__bf16*)(w + WS_BCG);
  __bf16* hs = (__bf16*)(w + WS_HS);

  k_prep<<<8, 256, 0, stream>>>(Wt, Wc, w);
  k_gemm_h<<<625, 256, 0, stream>>>(nf, Btg, bt, Wa, eidx, deg, hs, p2, q2);
  k_scan<<<1, 1024, 0, stream>>>(deg, offs, cursor);
  k_att<<<625, 256, 0, stream>>>(eidx, (const float4*)p2, (const float4*)q2,
                                 ba, cursor, tgts, exw, S);
  k_agg<<<2500, 256, 0, stream>>>(tgts, offs, exw, S, hs);
  k_gemm_out<<<313, 256, 0, stream>>>(hs, Bcg, bc, out);
}

// Round 5
// 160.749 us; speedup vs baseline: 1.4740x; 1.0232x over previous
//
#include <hip/hip_runtime.h>

// Problem constants (match reference setup_inputs)
#define BB 4
#define NN 10000
#define FF 128
#define UU 128
#define EE 160000

typedef __bf16 bf16x8 __attribute__((ext_vector_type(8)));
typedef float  f32x4  __attribute__((ext_vector_type(4)));

// ws layout (bytes)
#define WS_S      0         // float S (4 B)
#define WS_DEG    256       // int[10000]
#define WS_OFFS   40448     // int[10001]
#define WS_CUR    80640     // int[10000]
#define WS_TGT    120832    // int[160000]            (CSR-ordered tgt)
#define WS_EXW    760832    // float exwT[4][160000]  (CSR-ordered, batch-planar)
#define WS_P      3320832   // float[40000]  p2[n][b] (node-major float4)
#define WS_Q      3480832   // float[40000]  q2[n][b]
#define WS_BTG    3640832   // bf16 swizzled W_t (32 KB)
#define WS_BCG    3673600   // bf16 swizzled W_c (64 KB)
#define WS_HS     3739136   // bf16 hs2[10000][4][256] (h | scat interleaved)

// ---------------------------------------------------------------------------
// k_prep: zero S+deg; pre-swizzle W_t and W_c into bf16 MFMA-frag layout.
__global__ __launch_bounds__(256) void k_prep(const float* __restrict__ Wt,
                                              const float* __restrict__ Wc,
                                              char* __restrict__ ws) {
  const int gid = blockIdx.x * 256 + threadIdx.x;  // 8 blocks -> 2048 threads
  uint4* zp = (uint4*)ws;
  uint4 z = {0u, 0u, 0u, 0u};
  for (int i = gid; i < 2528; i += 2048) zp[i] = z;

  __bf16* Btg = (__bf16*)(ws + WS_BTG);
  __bf16* Bcg = (__bf16*)(ws + WS_BCG);
  {
    int i = gid;
    int n = i & 127, kb8 = i >> 7;  // kb8 in [0,16)
    int kc = kb8 >> 2, kbq = kb8 & 3;
    int lane = (n & 15) | (kbq << 4), c = n >> 4;
    const float* src = Wt + (size_t)kb8 * 8 * 128 + n;
    bf16x8 v;
#pragma unroll
    for (int j = 0; j < 8; ++j) v[j] = (__bf16)src[(size_t)j * 128];
    *(bf16x8*)(Btg + ((kc * 8 + c) * 512 + lane * 8)) = v;
  }
#pragma unroll
  for (int it = 0; it < 2; ++it) {
    int i = gid + it * 2048;
    int n = i & 127, kb8 = i >> 7;  // kb8 in [0,32)
    int kc = kb8 >> 2, kbq = kb8 & 3;
    int lane = (n & 15) | (kbq << 4), c = n >> 4;
    const float* src = Wc + (size_t)kb8 * 8 * 128 + n;
    bf16x8 v;
#pragma unroll
    for (int j = 0; j < 8; ++j) v[j] = (__bf16)src[(size_t)j * 128];
    *(bf16x8*)(Bcg + ((kc * 8 + c) * 512 + lane * 8)) = v;
  }
}

// ---------------------------------------------------------------------------
// GEMM1: h = relu(nf @ W_t + b_t) -> hs2[n][b][0:128]; fused p2/q2 and degree
// count. 313 blocks x 512 threads (8 waves, 128 rows/block).
__global__ __launch_bounds__(512) void k_gemm_h(
    const float* __restrict__ nf, const __bf16* __restrict__ Btg,
    const float* __restrict__ bt, const float* __restrict__ Wa,
    const int* __restrict__ eidx, int* __restrict__ deg,
    __bf16* __restrict__ hs, float* __restrict__ p2, float* __restrict__ q2) {
  {
    int e = blockIdx.x * 512 + threadIdx.x;
    if (e < EE) atomicAdd(&deg[eidx[2 * e]], 1);
  }
  __shared__ __bf16 Bt[32 * 512];  // 32 KB
  const int tid = threadIdx.x;
  {
    uint4* d = (uint4*)Bt;
    const uint4* s = (const uint4*)Btg;
#pragma unroll
    for (int i = tid; i < 2048; i += 512) d[i] = s[i];
  }
  __syncthreads();

  const int wid = tid >> 6, lane = tid & 63;
  const int lr = lane & 15, lg = lane >> 4;
  const int row0 = blockIdx.x * 128 + wid * 16;

  f32x4 acc[8];
#pragma unroll
  for (int c = 0; c < 8; ++c)
#pragma unroll
    for (int r = 0; r < 4; ++r) acc[c][r] = 0.f;

  const int arow = min(row0 + lr, 39999);  // tail clamp (loads only)

#pragma unroll
  for (int k0 = 0; k0 < 128; k0 += 32) {
    int kk = k0 + lg * 8;
    const float4* ap = (const float4*)(nf + (size_t)arow * 128 + kk);
    float4 a0 = ap[0], a1 = ap[1];
    bf16x8 af;
    af[0] = (__bf16)a0.x; af[1] = (__bf16)a0.y; af[2] = (__bf16)a0.z; af[3] = (__bf16)a0.w;
    af[4] = (__bf16)a1.x; af[5] = (__bf16)a1.y; af[6] = (__bf16)a1.z; af[7] = (__bf16)a1.w;
#pragma unroll
    for (int c = 0; c < 8; ++c) {
      bf16x8 bf = *(const bf16x8*)(Bt + (((k0 >> 5) << 3) + c) * 512 + lane * 8);
      acc[c] = __builtin_amdgcn_mfma_f32_16x16x32_bf16(af, bf, acc[c], 0, 0, 0);
    }
  }

#pragma unroll
  for (int r = 0; r < 4; ++r) {
    int row = row0 + lg * 4 + r;  // m = b*NN + n
    bool ok = row < 40000;
    int b = row / NN;
    int n = row - b * NN;
    size_t dst = ((size_t)n * 4 + b) * 256;  // hs2 row
    float pr = 0.f, qr = 0.f;
#pragma unroll
    for (int c = 0; c < 8; ++c) {
      int col = c * 16 + lr;
      float v = acc[c][r] + bt[col];
      v = fmaxf(v, 0.f);
      if (ok) hs[dst + col] = (__bf16)v;
      pr += v * Wa[col];
      qr += v * Wa[128 + col];
    }
#pragma unroll
    for (int m = 1; m < 16; m <<= 1) {
      pr += __shfl_xor(pr, m);
      qr += __shfl_xor(qr, m);
    }
    if (lr == 0 && ok) {
      p2[n * 4 + b] = pr;
      q2[n * 4 + b] = qr;
    }
  }
}

// ---------------------------------------------------------------------------
// k_scan: exclusive scan of deg[10000] -> offs, cursor. One block, shfl scan.
__global__ __launch_bounds__(1024) void k_scan(const int* __restrict__ deg,
                                               int* __restrict__ offs,
                                               int* __restrict__ cursor) {
  const int t = threadIdx.x, lane = t & 63, wv = t >> 6;
  const int base = t * 10;
  int local[10];
  int s = 0;
#pragma unroll
  for (int i = 0; i < 10; ++i) {
    int v = (base + i < NN) ? deg[base + i] : 0;
    local[i] = s;
    s += v;
  }
  const int tsum = s;
#pragma unroll
  for (int off = 1; off < 64; off <<= 1) {
    int v = __shfl_up(s, off);
    if (lane >= off) s += v;
  }
  __shared__ int wsum[16];
  if (lane == 63) wsum[wv] = s;
  __syncthreads();
  int add = 0;
#pragma unroll
  for (int w = 0; w < 16; ++w) {
    int v = wsum[w];
    if (w < wv) add += v;
  }
  int pre = add + s - tsum;
#pragma unroll
  for (int i = 0; i < 10; ++i) {
    int idx = base + i;
    if (idx < NN) {
      int o = pre + local[i];
      offs[idx] = o;
      cursor[idx] = o;
    }
  }
  if (t == 1023) offs[NN] = pre + tsum;  // == EE
}

// ---------------------------------------------------------------------------
// k_att: one thread per EDGE. Computes all 4 batches' exp(tanh(...)), claims
// the CSR slot, writes tgts[pos] + exwT[b][pos] (batch-planar), accumulates S.
__global__ __launch_bounds__(256) void k_att(const int* __restrict__ eidx,
                                             const float4* __restrict__ p2,
                                             const float4* __restrict__ q2,
                                             const float* __restrict__ ba,
                                             int* __restrict__ cursor,
                                             int* __restrict__ tgts,
                                             float* __restrict__ exwT,
                                             float* __restrict__ S) {
  int e = blockIdx.x * 256 + threadIdx.x;  // < 160000 exactly
  int s = eidx[2 * e], t = eidx[2 * e + 1];
  float4 pv = p2[s];
  float4 qv = q2[t];
  float bias = ba[0];
#define ATT(pc, qc, out)                              \
  {                                                   \
    float a = (pc) + (qc) + bias;                     \
    float z = __expf(2.f * a);                        \
    float th = 1.f - __fdividef(2.f, z + 1.f);        \
    (out) = __expf(th);                               \
  }
  float v0, v1, v2, v3;
  ATT(pv.x, qv.x, v0)
  ATT(pv.y, qv.y, v1)
  ATT(pv.z, qv.z, v2)
  ATT(pv.w, qv.w, v3)
#undef ATT
  int pos = atomicAdd(&cursor[s], 1);
  tgts[pos] = t;
  exwT[pos] = v0;
  exwT[EE + pos] = v1;
  exwT[2 * EE + pos] = v2;
  exwT[3 * EE + pos] = v3;
  float vs = v0 + v1 + v2 + v3;
#pragma unroll
  for (int m = 1; m < 64; m <<= 1) vs += __shfl_xor(vs, m);
  __shared__ float part[4];
  int wid = threadIdx.x >> 6, lane = threadIdx.x & 63;
  if (lane == 0) part[wid] = vs;
  __syncthreads();
  if (threadIdx.x == 0) atomicAdd(S, part[0] + part[1] + part[2] + part[3]);
}

// ---------------------------------------------------------------------------
// k_agg: one wave per node. Per edge: ONE dwordx4/lane covers the node's
// entire 4-batch h gather. Batch phase (16 edges): lane L holds tgt of edge
// base+(L&15) and weight-component (L>>4) of that edge; per edge one bpermute
// each for tgt and weight. Edges unrolled x4 (4 gathers in flight).
__global__ __launch_bounds__(256) void k_agg(
    const int* __restrict__ tgts, const int* __restrict__ offs,
    const float* __restrict__ exwT, const float* __restrict__ S,
    __bf16* __restrict__ hs) {
  const int wid = threadIdx.x >> 6, lane = threadIdx.x & 63;
  const int n = blockIdx.x * 4 + wid;  // < 10000 exactly (2500 blocks)
  const int myb = lane >> 4, sub = lane & 15;
  const int o0 = offs[n], o1 = offs[n + 1];
  const uint4* __restrict__ hu4 = (const uint4*)hs;  // 128 uint4 per node
  float acc[8];
#pragma unroll
  for (int i = 0; i < 8; ++i) acc[i] = 0.f;

  const int lbase = myb * 32 + sub;  // lane's uint4 slot within node (h half)
  const int wsrc = myb << 4;
  for (int base = o0; base < o1; base += 16) {
    int idx = base + sub;
    bool valid = idx < o1;
    int t_l = valid ? tgts[idx] : 0;
    float w_l = valid ? exwT[(size_t)myb * EE + idx] : 0.f;
    int cnt = min(16, o1 - base);
    for (int j = 0; j < cnt; j += 4) {
      int t0 = __shfl(t_l, j + 0);
      int t1 = __shfl(t_l, j + 1);
      int t2 = __shfl(t_l, j + 2);
      int t3 = __shfl(t_l, j + 3);
      float m0 = __shfl(w_l, wsrc | (j + 0));
      float m1 = __shfl(w_l, wsrc | (j + 1));
      float m2 = __shfl(w_l, wsrc | (j + 2));
      float m3 = __shfl(w_l, wsrc | (j + 3));
      uint4 va = hu4[(size_t)t0 * 128 + lbase];
      uint4 vb = hu4[(size_t)t1 * 128 + lbase];
      uint4 vc = hu4[(size_t)t2 * 128 + lbase];
      uint4 vd = hu4[(size_t)t3 * 128 + lbase];
#define LO(x) __uint_as_float((x) << 16)
#define HI(x) __uint_as_float((x)&0xffff0000u)
#define ACC(m, v)                                                   \
  acc[0] = fmaf((m), LO((v).x), acc[0]);                            \
  acc[1] = fmaf((m), HI((v).x), acc[1]);                            \
  acc[2] = fmaf((m), LO((v).y), acc[2]);                            \
  acc[3] = fmaf((m), HI((v).y), acc[3]);                            \
  acc[4] = fmaf((m), LO((v).z), acc[4]);                            \
  acc[5] = fmaf((m), HI((v).z), acc[5]);                            \
  acc[6] = fmaf((m), LO((v).w), acc[6]);                            \
  acc[7] = fmaf((m), HI((v).w), acc[7]);
      ACC(m0, va)
      ACC(m1, vb)
      ACC(m2, vc)
      ACC(m3, vd)
#undef ACC
#undef LO
#undef HI
    }
  }
  const float invS = 1.0f / S[0];
  uint4 st;
  unsigned* sp = (unsigned*)&st;
#pragma unroll
  for (int i = 0; i < 4; ++i) {
    unsigned ux = __float_as_uint(acc[2 * i] * invS);
    ux = (ux + 0x7fffu + ((ux >> 16) & 1u)) >> 16;
    unsigned uy = __float_as_uint(acc[2 * i + 1] * invS);
    uy = (uy + 0x7fffu + ((uy >> 16) & 1u)) >> 16;
    sp[i] = ux | (uy << 16);
  }
  ((uint4*)hs)[(size_t)n * 128 + myb * 32 + 16 + sub] = st;  // scat half
}

// ---------------------------------------------------------------------------
// GEMM2: out = relu(hs2 @ W_c + b_c)  (M=40000 rows m=n*4+b, K=256, N=128)
// 313 blocks x 512 threads (8 waves, 128 rows/block, one 16-row tile/wave).
__global__ __launch_bounds__(512) void k_gemm_out(
    const __bf16* __restrict__ hs, const __bf16* __restrict__ Bcg,
    const float* __restrict__ bc, float* __restrict__ out) {
  __shared__ __bf16 Bt[64 * 512];  // 64 KB
  const int tid = threadIdx.x;
  {
    uint4* d = (uint4*)Bt;
    const uint4* s = (const uint4*)Bcg;
#pragma unroll
    for (int i = tid; i < 4096; i += 512) d[i] = s[i];
  }
  __syncthreads();

  const int wid = tid >> 6, lane = tid & 63;
  const int lr = lane & 15, lg = lane >> 4;
  const int row0 = blockIdx.x * 128 + wid * 16;

  f32x4 acc[8];
#pragma unroll
  for (int c = 0; c < 8; ++c)
#pragma unroll
    for (int r = 0; r < 4; ++r) acc[c][r] = 0.f;

  const int arow = min(row0 + lr, 39999);  // tail clamp (loads only)

#pragma unroll
  for (int k0 = 0; k0 < 256; k0 += 32) {
    int kk = k0 + lg * 8;
    bf16x8 af = *(const bf16x8*)(hs + (size_t)arow * 256 + kk);
#pragma unroll
    for (int c = 0; c < 8; ++c) {
      bf16x8 bf = *(const bf16x8*)(Bt + (((k0 >> 5) << 3) + c) * 512 + lane * 8);
      acc[c] = __builtin_amdgcn_mfma_f32_16x16x32_bf16(af, bf, acc[c], 0, 0, 0);
    }
  }

#pragma unroll
  for (int r = 0; r < 4; ++r) {
    int m = row0 + lg * 4 + r;  // hs2 row = n*4+b
    if (m < 40000) {
      int n = m >> 2, b = m & 3;
      size_t orow = ((size_t)b * NN + n) * 128;
#pragma unroll
      for (int c = 0; c < 8; ++c) {
        int col = c * 16 + lr;
        float v = acc[c][r] + bc[col];
        out[orow + col] = fmaxf(v, 0.f);
      }
    }
  }
}

// ---------------------------------------------------------------------------
extern "C" void kernel_launch(void* const* d_in, const int* in_sizes, int n_in,
                              void* d_out, int out_size, void* d_ws,
                              size_t ws_size, hipStream_t stream) {
  const float* nf = (const float*)d_in[0];
  const int* eidx = (const int*)d_in[1];
  const float* Wt = (const float*)d_in[2];
  const float* bt = (const float*)d_in[3];
  const float* Wa = (const float*)d_in[4];
  const float* ba = (const float*)d_in[5];
  const float* Wc = (const float*)d_in[6];
  const float* bc = (const float*)d_in[7];
  float* out = (float*)d_out;

  char* w = (char*)d_ws;
  float* S = (float*)(w + WS_S);
  int* deg = (int*)(w + WS_DEG);
  int* offs = (int*)(w + WS_OFFS);
  int* cursor = (int*)(w + WS_CUR);
  int* tgts = (int*)(w + WS_TGT);
  float* exwT = (float*)(w + WS_EXW);
  float* p2 = (float*)(w + WS_P);
  float* q2 = (float*)(w + WS_Q);
  __bf16* Btg = (__bf16*)(w + WS_BTG);
  __bf16* Bcg = (__bf16*)(w + WS_BCG);
  __bf16* hs = (__bf16*)(w + WS_HS);

  k_prep<<<8, 256, 0, stream>>>(Wt, Wc, w);
  k_gemm_h<<<313, 512, 0, stream>>>(nf, Btg, bt, Wa, eidx, deg, hs, p2, q2);
  k_scan<<<1, 1024, 0, stream>>>(deg, offs, cursor);
  k_att<<<625, 256, 0, stream>>>(eidx, (const float4*)p2, (const float4*)q2,
                                 ba, cursor, tgts, exwT, S);
  k_agg<<<2500, 256, 0, stream>>>(tgts, offs, exwT, S, hs);
  k_gemm_out<<<313, 512, 0, stream>>>(hs, Bcg, bc, out);
}

// Round 6
// 152.987 us; speedup vs baseline: 1.5488x; 1.0507x over previous
//
#include <hip/hip_runtime.h>

// Problem constants (match reference setup_inputs)
#define BB 4
#define NN 10000
#define FF 128
#define UU 128
#define EE 160000

typedef __bf16 bf16x8 __attribute__((ext_vector_type(8)));
typedef float  f32x4  __attribute__((ext_vector_type(4)));
typedef float  f32x2  __attribute__((ext_vector_type(2)));

// ws layout (bytes)
#define WS_S      0         // float S (4 B)
#define WS_DEG    256       // int[10000]
#define WS_OFFS   40448     // int[10001]
#define WS_CUR    80640     // int[10000]
#define WS_TGT    120832    // int[160000]            (CSR-ordered tgt)
#define WS_EXW    760832    // float4[160000]         (CSR-ordered weights)
#define WS_P      3320832   // float[40000]  p2[n][b] (node-major float4)
#define WS_Q      3480832   // float[40000]  q2[n][b]
#define WS_BTG    3640832   // bf16 swizzled W_t (32 KB)
#define WS_BCG    3673600   // bf16 swizzled W_c (64 KB, K-half row-remapped)
#define WS_HS     3739136   // bf16 hs2[10000][4][256] (h | scat interleaved)
#define WS_H8     24219136  // fp8  h8[10000][4][128]  (gather copy; chunk byte c = col 16c+lr)

// ---------------------------------------------------------------------------
// k_prep: zero S+deg; pre-swizzle W_t and W_c into bf16 MFMA-frag layout.
// W_c K-half (k'>=128) uses the sigma remap: frag position t=k'-128=(sub*8+c)
// sources Wc row 128 + 16*c + sub, matching h8/scat's permuted column order.
__global__ __launch_bounds__(256) void k_prep(const float* __restrict__ Wt,
                                              const float* __restrict__ Wc,
                                              char* __restrict__ ws) {
  const int gid = blockIdx.x * 256 + threadIdx.x;  // 8 blocks -> 2048 threads
  uint4* zp = (uint4*)ws;
  uint4 z = {0u, 0u, 0u, 0u};
  for (int i = gid; i < 2528; i += 2048) zp[i] = z;

  __bf16* Btg = (__bf16*)(ws + WS_BTG);
  __bf16* Bcg = (__bf16*)(ws + WS_BCG);
  {
    int i = gid;
    int n = i & 127, kb8 = i >> 7;  // kb8 in [0,16)
    int kc = kb8 >> 2, kbq = kb8 & 3;
    int lane = (n & 15) | (kbq << 4), c = n >> 4;
    const float* src = Wt + (size_t)kb8 * 8 * 128 + n;
    bf16x8 v;
#pragma unroll
    for (int j = 0; j < 8; ++j) v[j] = (__bf16)src[(size_t)j * 128];
    *(bf16x8*)(Btg + ((kc * 8 + c) * 512 + lane * 8)) = v;
  }
#pragma unroll
  for (int it = 0; it < 2; ++it) {
    int i = gid + it * 2048;
    int n = i & 127, kb8 = i >> 7;  // kb8 in [0,32)
    int kc = kb8 >> 2, kbq = kb8 & 3;
    int lane = (n & 15) | (kbq << 4), c = n >> 4;
    bf16x8 v;
    if (kb8 < 16) {  // K-low half: natural rows
      const float* src = Wc + (size_t)kb8 * 8 * 128 + n;
#pragma unroll
      for (int j = 0; j < 8; ++j) v[j] = (__bf16)src[(size_t)j * 128];
    } else {  // K-high half: sigma remap (sub = kb8-16, c = j -> row 128+16j+sub)
      int sub = kb8 - 16;
      const float* src = Wc + (size_t)(128 + sub) * 128 + n;
#pragma unroll
      for (int j = 0; j < 8; ++j) v[j] = (__bf16)src[(size_t)j * 16 * 128];
    }
    *(bf16x8*)(Bcg + ((kc * 8 + c) * 512 + lane * 8)) = v;
  }
}

// ---------------------------------------------------------------------------
// GEMM1: h = relu(nf @ W_t + b_t) -> hs2[n][b][0:128] (bf16) + h8 (fp8 copy,
// chunk layout); fused p2/q2 and degree count. 313 blocks x 512 threads.
__global__ __launch_bounds__(512) void k_gemm_h(
    const float* __restrict__ nf, const __bf16* __restrict__ Btg,
    const float* __restrict__ bt, const float* __restrict__ Wa,
    const int* __restrict__ eidx, int* __restrict__ deg,
    __bf16* __restrict__ hs, char* __restrict__ h8,
    float* __restrict__ p2, float* __restrict__ q2) {
  {
    int e = blockIdx.x * 512 + threadIdx.x;
    if (e < EE) atomicAdd(&deg[eidx[2 * e]], 1);
  }
  __shared__ __bf16 Bt[32 * 512];  // 32 KB
  const int tid = threadIdx.x;
  {
    uint4* d = (uint4*)Bt;
    const uint4* s = (const uint4*)Btg;
#pragma unroll
    for (int i = tid; i < 2048; i += 512) d[i] = s[i];
  }
  __syncthreads();

  const int wid = tid >> 6, lane = tid & 63;
  const int lr = lane & 15, lg = lane >> 4;
  const int row0 = blockIdx.x * 128 + wid * 16;

  f32x4 acc[8];
#pragma unroll
  for (int c = 0; c < 8; ++c)
#pragma unroll
    for (int r = 0; r < 4; ++r) acc[c][r] = 0.f;

  const int arow = min(row0 + lr, 39999);  // tail clamp (loads only)

#pragma unroll
  for (int k0 = 0; k0 < 128; k0 += 32) {
    int kk = k0 + lg * 8;
    const float4* ap = (const float4*)(nf + (size_t)arow * 128 + kk);
    float4 a0 = ap[0], a1 = ap[1];
    bf16x8 af;
    af[0] = (__bf16)a0.x; af[1] = (__bf16)a0.y; af[2] = (__bf16)a0.z; af[3] = (__bf16)a0.w;
    af[4] = (__bf16)a1.x; af[5] = (__bf16)a1.y; af[6] = (__bf16)a1.z; af[7] = (__bf16)a1.w;
#pragma unroll
    for (int c = 0; c < 8; ++c) {
      bf16x8 bf = *(const bf16x8*)(Bt + (((k0 >> 5) << 3) + c) * 512 + lane * 8);
      acc[c] = __builtin_amdgcn_mfma_f32_16x16x32_bf16(af, bf, acc[c], 0, 0, 0);
    }
  }

#pragma unroll
  for (int r = 0; r < 4; ++r) {
    int row = row0 + lg * 4 + r;  // m = b*NN + n
    bool ok = row < 40000;
    int b = row / NN;
    int n = row - b * NN;
    size_t dst = ((size_t)n * 4 + b) * 256;  // hs2 row
    float vv[8];
    float pr = 0.f, qr = 0.f;
#pragma unroll
    for (int c = 0; c < 8; ++c) {
      int col = c * 16 + lr;
      float v = acc[c][r] + bt[col];
      v = fmaxf(v, 0.f);
      vv[c] = v;
      if (ok) hs[dst + col] = (__bf16)v;
      pr += v * Wa[col];
      qr += v * Wa[128 + col];
    }
    // fp8 chunk: byte c = col 16c+lr
    int d0 = __builtin_amdgcn_cvt_pk_fp8_f32(vv[0], vv[1], 0, false);
    d0 = __builtin_amdgcn_cvt_pk_fp8_f32(vv[2], vv[3], d0, true);
    int d1 = __builtin_amdgcn_cvt_pk_fp8_f32(vv[4], vv[5], 0, false);
    d1 = __builtin_amdgcn_cvt_pk_fp8_f32(vv[6], vv[7], d1, true);
    if (ok) {
      uint2 st = make_uint2((unsigned)d0, (unsigned)d1);
      *(uint2*)(h8 + ((size_t)n * 4 + b) * 128 + lr * 8) = st;
    }
#pragma unroll
    for (int m = 1; m < 16; m <<= 1) {
      pr += __shfl_xor(pr, m);
      qr += __shfl_xor(qr, m);
    }
    if (lr == 0 && ok) {
      p2[n * 4 + b] = pr;
      q2[n * 4 + b] = qr;
    }
  }
}

// ---------------------------------------------------------------------------
// k_scan: exclusive scan of deg[10000] -> offs, cursor. One block, shfl scan.
__global__ __launch_bounds__(1024) void k_scan(const int* __restrict__ deg,
                                               int* __restrict__ offs,
                                               int* __restrict__ cursor) {
  const int t = threadIdx.x, lane = t & 63, wv = t >> 6;
  const int base = t * 10;
  int local[10];
  int s = 0;
#pragma unroll
  for (int i = 0; i < 10; ++i) {
    int v = (base + i < NN) ? deg[base + i] : 0;
    local[i] = s;
    s += v;
  }
  const int tsum = s;
#pragma unroll
  for (int off = 1; off < 64; off <<= 1) {
    int v = __shfl_up(s, off);
    if (lane >= off) s += v;
  }
  __shared__ int wsum[16];
  if (lane == 63) wsum[wv] = s;
  __syncthreads();
  int add = 0;
#pragma unroll
  for (int w = 0; w < 16; ++w) {
    int v = wsum[w];
    if (w < wv) add += v;
  }
  int pre = add + s - tsum;
#pragma unroll
  for (int i = 0; i < 10; ++i) {
    int idx = base + i;
    if (idx < NN) {
      int o = pre + local[i];
      offs[idx] = o;
      cursor[idx] = o;
    }
  }
  if (t == 1023) offs[NN] = pre + tsum;  // == EE
}

// ---------------------------------------------------------------------------
// k_att: one thread per EDGE. All 4 batches' exp(tanh(...)); claims the CSR
// slot; ONE float4 store (exw) + one int store (tgt); accumulates S.
__global__ __launch_bounds__(256) void k_att(const int* __restrict__ eidx,
                                             const float4* __restrict__ p2,
                                             const float4* __restrict__ q2,
                                             const float* __restrict__ ba,
                                             int* __restrict__ cursor,
                                             int* __restrict__ tgts,
                                             float4* __restrict__ exw,
                                             float* __restrict__ S) {
  int e = blockIdx.x * 256 + threadIdx.x;  // < 160000 exactly
  int s = eidx[2 * e], t = eidx[2 * e + 1];
  float4 pv = p2[s];
  float4 qv = q2[t];
  float bias = ba[0];
#define ATT(pc, qc, out)                              \
  {                                                   \
    float a = (pc) + (qc) + bias;                     \
    float z = __expf(2.f * a);                        \
    float th = 1.f - __fdividef(2.f, z + 1.f);        \
    (out) = __expf(th);                               \
  }
  float v0, v1, v2, v3;
  ATT(pv.x, qv.x, v0)
  ATT(pv.y, qv.y, v1)
  ATT(pv.z, qv.z, v2)
  ATT(pv.w, qv.w, v3)
#undef ATT
  int pos = atomicAdd(&cursor[s], 1);
  tgts[pos] = t;
  exw[pos] = make_float4(v0, v1, v2, v3);
  float vs = v0 + v1 + v2 + v3;
#pragma unroll
  for (int m = 1; m < 64; m <<= 1) vs += __shfl_xor(vs, m);
  __shared__ float part[4];
  int wid = threadIdx.x >> 6, lane = threadIdx.x & 63;
  if (lane == 0) part[wid] = vs;
  __syncthreads();
  if (threadIdx.x == 0) atomicAdd(S, part[0] + part[1] + part[2] + part[3]);
}

// ---------------------------------------------------------------------------
// k_agg: one wave per node. Per edge: ONE 8 B load/lane from the fp8 h copy
// covers all 4 batches (lane = batch myb, chunk sub). acc[c] <-> col 16c+sub;
// the scat-store position sub*8+c is compensated by k_prep's Bcg row remap.
__global__ __launch_bounds__(256) void k_agg(
    const int* __restrict__ tgts, const int* __restrict__ offs,
    const float4* __restrict__ exw, const float* __restrict__ S,
    const char* __restrict__ h8, __bf16* __restrict__ hs) {
  const int wid = threadIdx.x >> 6, lane = threadIdx.x & 63;
  const int n = blockIdx.x * 4 + wid;  // < 10000 exactly (2500 blocks)
  const int myb = lane >> 4, sub = lane & 15;
  const int o0 = offs[n], o1 = offs[n + 1];
  const uint2* __restrict__ h8u = (const uint2*)h8;  // 64 uint2 per node
  float acc[8];
#pragma unroll
  for (int i = 0; i < 8; ++i) acc[i] = 0.f;

  const int lslot = myb * 16 + sub;  // lane's uint2 slot within a node block
  const int wsrc = myb << 4;
  for (int base = o0; base < o1; base += 16) {
    int idx = base + sub;
    bool valid = idx < o1;
    int t_l = valid ? tgts[idx] : 0;
    float4 w4 = valid ? exw[idx] : make_float4(0.f, 0.f, 0.f, 0.f);
    float w_l = (myb == 0) ? w4.x : (myb == 1) ? w4.y : (myb == 2) ? w4.z : w4.w;
    int cnt = min(16, o1 - base);
    for (int j = 0; j < cnt; j += 4) {
      int t0 = __shfl(t_l, j + 0);
      int t1 = __shfl(t_l, j + 1);
      int t2 = __shfl(t_l, j + 2);
      int t3 = __shfl(t_l, j + 3);
      float m0 = __shfl(w_l, wsrc | (j + 0));
      float m1 = __shfl(w_l, wsrc | (j + 1));
      float m2 = __shfl(w_l, wsrc | (j + 2));
      float m3 = __shfl(w_l, wsrc | (j + 3));
      uint2 va = h8u[(size_t)t0 * 64 + lslot];
      uint2 vb = h8u[(size_t)t1 * 64 + lslot];
      uint2 vc = h8u[(size_t)t2 * 64 + lslot];
      uint2 vd = h8u[(size_t)t3 * 64 + lslot];
#define ACC8(m, v)                                                        \
  {                                                                       \
    f32x2 f01 = __builtin_amdgcn_cvt_pk_f32_fp8((int)(v).x, false);       \
    f32x2 f23 = __builtin_amdgcn_cvt_pk_f32_fp8((int)(v).x, true);        \
    f32x2 f45 = __builtin_amdgcn_cvt_pk_f32_fp8((int)(v).y, false);       \
    f32x2 f67 = __builtin_amdgcn_cvt_pk_f32_fp8((int)(v).y, true);        \
    acc[0] = fmaf((m), f01.x, acc[0]); acc[1] = fmaf((m), f01.y, acc[1]); \
    acc[2] = fmaf((m), f23.x, acc[2]); acc[3] = fmaf((m), f23.y, acc[3]); \
    acc[4] = fmaf((m), f45.x, acc[4]); acc[5] = fmaf((m), f45.y, acc[5]); \
    acc[6] = fmaf((m), f67.x, acc[6]); acc[7] = fmaf((m), f67.y, acc[7]); \
  }
      ACC8(m0, va)
      ACC8(m1, vb)
      ACC8(m2, vc)
      ACC8(m3, vd)
#undef ACC8
    }
  }
  const float invS = 1.0f / S[0];
  uint4 st;
  unsigned* sp = (unsigned*)&st;
#pragma unroll
  for (int i = 0; i < 4; ++i) {
    unsigned ux = __float_as_uint(acc[2 * i] * invS);
    ux = (ux + 0x7fffu + ((ux >> 16) & 1u)) >> 16;
    unsigned uy = __float_as_uint(acc[2 * i + 1] * invS);
    uy = (uy + 0x7fffu + ((uy >> 16) & 1u)) >> 16;
    sp[i] = ux | (uy << 16);
  }
  ((uint4*)hs)[(size_t)n * 128 + myb * 32 + 16 + sub] = st;  // scat half
}

// ---------------------------------------------------------------------------
// GEMM2: out = relu(hs2 @ W_c + b_c)  (M=40000 rows m=n*4+b, K=256, N=128)
// 313 blocks x 512 threads; Bcg's K-half row remap matches scat's layout.
__global__ __launch_bounds__(512) void k_gemm_out(
    const __bf16* __restrict__ hs, const __bf16* __restrict__ Bcg,
    const float* __restrict__ bc, float* __restrict__ out) {
  __shared__ __bf16 Bt[64 * 512];  // 64 KB
  const int tid = threadIdx.x;
  {
    uint4* d = (uint4*)Bt;
    const uint4* s = (const uint4*)Bcg;
#pragma unroll
    for (int i = tid; i < 4096; i += 512) d[i] = s[i];
  }
  __syncthreads();

  const int wid = tid >> 6, lane = tid & 63;
  const int lr = lane & 15, lg = lane >> 4;
  const int row0 = blockIdx.x * 128 + wid * 16;

  f32x4 acc[8];
#pragma unroll
  for (int c = 0; c < 8; ++c)
#pragma unroll
    for (int r = 0; r < 4; ++r) acc[c][r] = 0.f;

  const int arow = min(row0 + lr, 39999);  // tail clamp (loads only)

#pragma unroll
  for (int k0 = 0; k0 < 256; k0 += 32) {
    int kk = k0 + lg * 8;
    bf16x8 af = *(const bf16x8*)(hs + (size_t)arow * 256 + kk);
#pragma unroll
    for (int c = 0; c < 8; ++c) {
      bf16x8 bf = *(const bf16x8*)(Bt + (((k0 >> 5) << 3) + c) * 512 + lane * 8);
      acc[c] = __builtin_amdgcn_mfma_f32_16x16x32_bf16(af, bf, acc[c], 0, 0, 0);
    }
  }

#pragma unroll
  for (int r = 0; r < 4; ++r) {
    int m = row0 + lg * 4 + r;  // hs2 row = n*4+b
    if (m < 40000) {
      int n = m >> 2, b = m & 3;
      size_t orow = ((size_t)b * NN + n) * 128;
#pragma unroll
      for (int c = 0; c < 8; ++c) {
        int col = c * 16 + lr;
        float v = acc[c][r] + bc[col];
        out[orow + col] = fmaxf(v, 0.f);
      }
    }
  }
}

// ---------------------------------------------------------------------------
extern "C" void kernel_launch(void* const* d_in, const int* in_sizes, int n_in,
                              void* d_out, int out_size, void* d_ws,
                              size_t ws_size, hipStream_t stream) {
  const float* nf = (const float*)d_in[0];
  const int* eidx = (const int*)d_in[1];
  const float* Wt = (const float*)d_in[2];
  const float* bt = (const float*)d_in[3];
  const float* Wa = (const float*)d_in[4];
  const float* ba = (const float*)d_in[5];
  const float* Wc = (const float*)d_in[6];
  const float* bc = (const float*)d_in[7];
  float* out = (float*)d_out;

  char* w = (char*)d_ws;
  float* S = (float*)(w + WS_S);
  int* deg = (int*)(w + WS_DEG);
  int* offs = (int*)(w + WS_OFFS);
  int* cursor = (int*)(w + WS_CUR);
  int* tgts = (int*)(w + WS_TGT);
  float4* exw = (float4*)(w + WS_EXW);
  float* p2 = (float*)(w + WS_P);
  float* q2 = (float*)(w + WS_Q);
  __bf16* Btg = (__bf16*)(w + WS_BTG);
  __bf16* Bcg = (__bf16*)(w + WS_BCG);
  __bf16* hs = (__bf16*)(w + WS_HS);
  char* h8 = w + WS_H8;

  k_prep<<<8, 256, 0, stream>>>(Wt, Wc, w);
  k_gemm_h<<<313, 512, 0, stream>>>(nf, Btg, bt, Wa, eidx, deg, hs, h8, p2, q2);
  k_scan<<<1, 1024, 0, stream>>>(deg, offs, cursor);
  k_att<<<625, 256, 0, stream>>>(eidx, (const float4*)p2, (const float4*)q2,
                                 ba, cursor, tgts, exw, S);
  k_agg<<<2500, 256, 0, stream>>>(tgts, offs, exw, S, h8, hs);
  k_gemm_out<<<313, 512, 0, stream>>>(hs, Bcg, bc, out);
}